// Round 8
// baseline (534.197 us; speedup 1.0000x reference)
//
#include <hip/hip_runtime.h>
#include <float.h>

// ---------------------------------------------------------------------------
// MPNN forward.  msg@w1 decomposed: per-node p=h@w1a, q=h@w1b (fused gemm_pq,
// f16 out, BN fused on A-load), per-edge ea@w1c; edge GEMM t1@w2 f16 MFMA.
// R18: barrier-free per-wave pipelining in node_agg.  Each wave owns an
// independent 16-edge micro-tile stream (groups == wid mod 4) and a private
// LDS slice; DS is in-order per wave so write->read needs only lgkmcnt --
// NO __syncthreads in the main loop.  Per-wave software pipeline: write
// payload(g) -> issue payload(g+1) -> issue idx(g+2) -> sched_barrier(0)
// -> lnod (binary search + 4 shfl, lnodS array deleted) -> GROUP_BODY.
// 24 independent gather streams/CU hide latency individually.
// R17 lesson kept: prefetch state small (16 VGPR) to avoid R15's spill.
// R13/R14: ea@w1c via MFMA (exact hi/lo f16 split, C-in = ps+q), C'+D fused
// per wave, binary-search lnod.
//
// ws (proven bound 38,601,024 B): hagg 12.8M | pqh 12.8M | ends 200K |
//   srcp 3.2M | part | stats(256f)  = 29.0 MB.
// d_out scratch: perm 3.2M | w2h 16K | w1ch 8K (dead before head writes).
// ---------------------------------------------------------------------------

typedef _Float16 half8 __attribute__((ext_vector_type(8)));
typedef _Float16 half4 __attribute__((ext_vector_type(4)));
typedef float floatx4 __attribute__((ext_vector_type(4)));

#define BN_EPS 1e-5f

__device__ __forceinline__ unsigned enc(float f) {
    unsigned u = __float_as_uint(f);
    return (u & 0x80000000u) ? ~u : (u | 0x80000000u);
}
__device__ __forceinline__ float dec(unsigned u) {
    return (u & 0x80000000u) ? __uint_as_float(u & 0x7fffffffu)
                             : __uint_as_float(~u);
}

// ---------------------------------------------------------------------------
// h0 GEMM: C[M][64] = relu(A[M][64] @ W[64][64] + bias)
// ---------------------------------------------------------------------------
__global__ __launch_bounds__(256) void gemm_h0(
    const float* __restrict__ A, const float* __restrict__ W,
    const float* __restrict__ bias, float* __restrict__ C, int M)
{
    __shared__ __align__(16) float Ws[64 * 64];
    __shared__ __align__(16) float As[64 * 68];

    const int t = threadIdx.x;
    const int m0 = blockIdx.x * 64;

    for (int i = t; i < 64 * 64; i += 256) Ws[i] = W[i];
    for (int rr = 0; rr < 64; rr += 16) {
        int r = rr + (t >> 4);
        int c4 = (t & 15) * 4;
        int row = m0 + r;
        float4 v = make_float4(0.f, 0.f, 0.f, 0.f);
        if (row < M) v = *(const float4*)&A[(size_t)row * 64 + c4];
        *(float4*)&As[r * 68 + c4] = v;
    }
    __syncthreads();

    const int tc = t & 15, tr = t >> 4;
    float4 acc[4];
    float4 bv = *(const float4*)&bias[tc * 4];
#pragma unroll
    for (int i = 0; i < 4; ++i) acc[i] = bv;
#pragma unroll 8
    for (int k = 0; k < 64; ++k) {
        float4 w = *(const float4*)&Ws[k * 64 + tc * 4];
#pragma unroll
        for (int i = 0; i < 4; ++i) {
            float a = As[(tr + i * 16) * 68 + k];
            acc[i].x = fmaf(a, w.x, acc[i].x);
            acc[i].y = fmaf(a, w.y, acc[i].y);
            acc[i].z = fmaf(a, w.z, acc[i].z);
            acc[i].w = fmaf(a, w.w, acc[i].w);
        }
    }
#pragma unroll
    for (int i = 0; i < 4; ++i) {
        int row = m0 + tr + i * 16;
        if (row < M) {
            float4 o = acc[i];
            o.x = fmaxf(o.x, 0.f); o.y = fmaxf(o.y, 0.f);
            o.z = fmaxf(o.z, 0.f); o.w = fmaxf(o.w, 0.f);
            *(float4*)&C[(size_t)row * 64 + tc * 4] = o;
        }
    }
}

// ---------------------------------------------------------------------------
// Fused p|q GEMM, f16 out, optional BN+relu on A-load.
// ---------------------------------------------------------------------------
template<bool BN>
__global__ __launch_bounds__(256) void gemm_pq(
    const float* __restrict__ A, const float* __restrict__ W,
    _Float16* __restrict__ PQ, const float* __restrict__ stats,
    const float* __restrict__ gamma, const float* __restrict__ beta, int M)
{
    __shared__ __align__(16) float Ws[64 * 128];
    __shared__ __align__(16) float As[64 * 68];

    const int t = threadIdx.x;
    const int m0 = blockIdx.x * 64;

    for (int i = t; i < 64 * 128; i += 256) {
        int k = i >> 7, n = i & 127;
        Ws[i] = W[(size_t)((n < 64 ? k : 64 + k)) * 64 + (n & 63)];
    }
    {
        int c4 = (t & 15) * 4;
        float sc[4], sh[4];
        if (BN) {
            float invM = 1.f / (float)M;
#pragma unroll
            for (int j = 0; j < 4; ++j) {
                int c = c4 + j;
                float mu = stats[c] * invM;
                float var = fmaxf(stats[64 + c] * invM - mu * mu, 0.f);
                float s = gamma[c] * rsqrtf(var + BN_EPS);
                sc[j] = s; sh[j] = beta[c] - mu * s;
            }
        }
        for (int rr = 0; rr < 64; rr += 16) {
            int r = rr + (t >> 4);
            int row = m0 + r;
            float4 v = make_float4(0.f, 0.f, 0.f, 0.f);
            if (row < M) v = *(const float4*)&A[(size_t)row * 64 + c4];
            if (BN) {
                v.x = fmaxf(fmaf(v.x, sc[0], sh[0]), 0.f);
                v.y = fmaxf(fmaf(v.y, sc[1], sh[1]), 0.f);
                v.z = fmaxf(fmaf(v.z, sc[2], sh[2]), 0.f);
                v.w = fmaxf(fmaf(v.w, sc[3], sh[3]), 0.f);
            }
            *(float4*)&As[r * 68 + c4] = v;
        }
    }
    __syncthreads();

    const int tc = t & 31, tr = t >> 5;
    float4 acc[8];
#pragma unroll
    for (int i = 0; i < 8; ++i) acc[i] = make_float4(0.f, 0.f, 0.f, 0.f);
#pragma unroll 8
    for (int k = 0; k < 64; ++k) {
        float4 w = *(const float4*)&Ws[k * 128 + tc * 4];
#pragma unroll
        for (int i = 0; i < 8; ++i) {
            float a = As[(tr + i * 8) * 68 + k];
            acc[i].x = fmaf(a, w.x, acc[i].x);
            acc[i].y = fmaf(a, w.y, acc[i].y);
            acc[i].z = fmaf(a, w.z, acc[i].z);
            acc[i].w = fmaf(a, w.w, acc[i].w);
        }
    }
#pragma unroll
    for (int i = 0; i < 8; ++i) {
        int row = m0 + tr + i * 8;
        if (row < M) {
            half4 o = { (_Float16)acc[i].x, (_Float16)acc[i].y,
                        (_Float16)acc[i].z, (_Float16)acc[i].w };
            *(half4*)&PQ[(size_t)row * 128 + tc * 4] = o;
        }
    }
}

// ---------------------------------------------------------------------------
// Fused head: out = relu(BN(h) @ w_m1 + b_m1) @ w_m2 + b_m2
// ---------------------------------------------------------------------------
__global__ __launch_bounds__(256) void head_fused(
    const float* __restrict__ hagg, const float* __restrict__ stats,
    const float* __restrict__ gamma, const float* __restrict__ beta,
    const float* __restrict__ w_m1, const float* __restrict__ b_m1,
    const float* __restrict__ w_m2, const float* __restrict__ b_m2,
    float* __restrict__ out, int M)
{
    __shared__ __align__(16) float Ws1[64 * 64];
    __shared__ __align__(16) float Ws2[64 * 32];
    __shared__ __align__(16) float As[64 * 68];
    __shared__ __align__(16) float Ts[64 * 68];

    const int t = threadIdx.x;
    const int m0 = blockIdx.x * 64;

    for (int i = t; i < 64 * 64; i += 256) Ws1[i] = w_m1[i];
    for (int i = t; i < 64 * 32; i += 256) Ws2[i] = w_m2[i];
    {
        int c4 = (t & 15) * 4;
        float sc[4], sh[4];
        float invM = 1.f / (float)M;
#pragma unroll
        for (int j = 0; j < 4; ++j) {
            int c = c4 + j;
            float mu = stats[c] * invM;
            float var = fmaxf(stats[64 + c] * invM - mu * mu, 0.f);
            float s = gamma[c] * rsqrtf(var + BN_EPS);
            sc[j] = s; sh[j] = beta[c] - mu * s;
        }
        for (int rr = 0; rr < 64; rr += 16) {
            int r = rr + (t >> 4);
            int row = m0 + r;
            float4 v = make_float4(0.f, 0.f, 0.f, 0.f);
            if (row < M) v = *(const float4*)&hagg[(size_t)row * 64 + c4];
            v.x = fmaxf(fmaf(v.x, sc[0], sh[0]), 0.f);
            v.y = fmaxf(fmaf(v.y, sc[1], sh[1]), 0.f);
            v.z = fmaxf(fmaf(v.z, sc[2], sh[2]), 0.f);
            v.w = fmaxf(fmaf(v.w, sc[3], sh[3]), 0.f);
            *(float4*)&As[r * 68 + c4] = v;
        }
    }
    __syncthreads();

    {
        const int tc = t & 15, tr = t >> 4;
        float4 acc[4];
        float4 bv = *(const float4*)&b_m1[tc * 4];
#pragma unroll
        for (int i = 0; i < 4; ++i) acc[i] = bv;
#pragma unroll 8
        for (int k = 0; k < 64; ++k) {
            float4 w = *(const float4*)&Ws1[k * 64 + tc * 4];
#pragma unroll
            for (int i = 0; i < 4; ++i) {
                float a = As[(tr + i * 16) * 68 + k];
                acc[i].x = fmaf(a, w.x, acc[i].x);
                acc[i].y = fmaf(a, w.y, acc[i].y);
                acc[i].z = fmaf(a, w.z, acc[i].z);
                acc[i].w = fmaf(a, w.w, acc[i].w);
            }
        }
#pragma unroll
        for (int i = 0; i < 4; ++i) {
            float4 o = acc[i];
            o.x = fmaxf(o.x, 0.f); o.y = fmaxf(o.y, 0.f);
            o.z = fmaxf(o.z, 0.f); o.w = fmaxf(o.w, 0.f);
            *(float4*)&Ts[(tr + i * 16) * 68 + tc * 4] = o;
        }
    }
    __syncthreads();

    {
        const int tc = t & 7, tr = t >> 3;
        float4 acc[2];
        float4 bv = *(const float4*)&b_m2[tc * 4];
        acc[0] = bv; acc[1] = bv;
#pragma unroll 8
        for (int k = 0; k < 64; ++k) {
            float4 w = *(const float4*)&Ws2[k * 32 + tc * 4];
#pragma unroll
            for (int i = 0; i < 2; ++i) {
                float a = Ts[(tr + i * 32) * 68 + k];
                acc[i].x = fmaf(a, w.x, acc[i].x);
                acc[i].y = fmaf(a, w.y, acc[i].y);
                acc[i].z = fmaf(a, w.z, acc[i].z);
                acc[i].w = fmaf(a, w.w, acc[i].w);
            }
        }
#pragma unroll
        for (int i = 0; i < 2; ++i) {
            int row = m0 + tr + i * 32;
            if (row < M) *(float4*)&out[(size_t)row * 32 + tc * 4] = acc[i];
        }
    }
}

// ---------------------------------------------------------------------------
// CSR build: hist -> multi-block exclusive scan -> fill(perm + srcp)
// ---------------------------------------------------------------------------
__global__ __launch_bounds__(256) void hist_tgt(const int* __restrict__ tgt,
                                                int* __restrict__ cnt, int E)
{
    int e = blockIdx.x * 256 + threadIdx.x;
    if (e < E) atomicAdd(&cnt[tgt[e]], 1);
}

__global__ __launch_bounds__(256) void scan_partial(const int* __restrict__ cnt,
                                                    int* __restrict__ part, int M)
{
    __shared__ int s[256];
    int i = blockIdx.x * 256 + threadIdx.x;
    s[threadIdx.x] = (i < M) ? cnt[i] : 0;
    __syncthreads();
    for (int off = 128; off > 0; off >>= 1) {
        if (threadIdx.x < off) s[threadIdx.x] += s[threadIdx.x + off];
        __syncthreads();
    }
    if (threadIdx.x == 0) part[blockIdx.x] = s[0];
}

__global__ __launch_bounds__(256) void scan_part2(int* __restrict__ part, int nb)
{
    __shared__ int s[256];
    int t = threadIdx.x;
    int v = (t < nb) ? part[t] : 0;
    s[t] = v;
    __syncthreads();
    for (int off = 1; off < 256; off <<= 1) {
        int a = (t >= off) ? s[t - off] : 0;
        __syncthreads();
        s[t] += a;
        __syncthreads();
    }
    if (t < nb) part[t] = s[t] - v;   // exclusive
}

__global__ __launch_bounds__(256) void scan_add(int* __restrict__ cnt,
                                                const int* __restrict__ part, int M)
{
    __shared__ int s[256];
    int t = threadIdx.x;
    int i = blockIdx.x * 256 + t;
    int v = (i < M) ? cnt[i] : 0;
    s[t] = v;
    __syncthreads();
    for (int off = 1; off < 256; off <<= 1) {
        int a = (t >= off) ? s[t - off] : 0;
        __syncthreads();
        s[t] += a;
        __syncthreads();
    }
    if (i < M) cnt[i] = part[blockIdx.x] + s[t] - v;
}

__global__ __launch_bounds__(256) void fill_csr(const int* __restrict__ tgt,
    const int* __restrict__ src, int* __restrict__ arr,
    int* __restrict__ perm, int* __restrict__ srcp, int E)
{
    int e = blockIdx.x * 256 + threadIdx.x;
    if (e < E) {
        int pos = atomicAdd(&arr[tgt[e]], 1);
        perm[pos] = e;
        srcp[pos] = src[e];
    }
}

// ---------------------------------------------------------------------------
// Pack w2 into f16 MFMA B-frag order; pack w1c as [w1c;w1c] K=32 B-frags
// (for the exact hi/lo-split ea MFMA); zero BN stats accumulators.
// ---------------------------------------------------------------------------
__global__ __launch_bounds__(256) void pack_w2(const float* __restrict__ w2,
                                               const float* __restrict__ w1,
                                               _Float16* __restrict__ w2h,
                                               _Float16* __restrict__ w1ch,
                                               float* __restrict__ stats)
{
    int id = blockIdx.x * 256 + threadIdx.x;
    if (id < 256) stats[id] = 0.f;
    if (id < 1024) {
        int l = id >> 9, rem = id & 511;
        int frag = rem >> 6, lane = rem & 63;
        int nt = frag >> 1, kc = frag & 1;
        const float* W = w2 + (size_t)l * 4096;
        _Float16* O = w2h + (size_t)l * 4096 + (frag * 64 + lane) * 8;
        int n = nt * 16 + (lane & 15);
        int k0 = kc * 32 + (lane >> 4) * 8;
#pragma unroll
        for (int j = 0; j < 8; ++j) O[j] = (_Float16)W[(k0 + j) * 64 + n];
    } else if (id < 1536) {
        // w1ch: B[k][n] = w1c[k & 15][n], K=32 (duplicated halves), 4 nt tiles
        int rem2 = id - 1024;
        int l = rem2 >> 8, rem = rem2 & 255;
        int nt = rem >> 6, lane = rem & 63;
        const float* W1C = w1 + (size_t)l * 144 * 64 + 128 * 64;
        _Float16* O = w1ch + (size_t)l * 2048 + (nt * 64 + lane) * 8;
        int n = nt * 16 + (lane & 15);
        int k0 = (lane >> 4) * 8;
#pragma unroll
        for (int j = 0; j < 8; ++j)
            O[j] = (_Float16)W1C[((k0 + j) & 15) * 64 + n];
    }
}

// ---------------------------------------------------------------------------
// Fused per-node edge-MLP + segmented max + BN stats.
//   R18: barrier-free per-wave micro-tile pipeline (16 edges/group, private
//   LDS slice per wave, no __syncthreads in main loop).  ea@w1c via MFMA
//   (exact hi/lo split), C'+D fused, lnod via binary search + shfl.
// ---------------------------------------------------------------------------
#define NPB 16
#define WED 16     // edges per wave micro-tile
#define TSH 72     // t1/q stride in halfs (144 B -> 2-way b128, free)
#define EST 40     // eash stride in halfs (80 B, 16B-aligned rows, 2-way)
#define QSL (WED * TSH)   // 1152 halfs per wave slice
#define ESL (WED * EST)   //  640 halfs per wave slice

__global__ __launch_bounds__(256, 4) void node_agg(
    const _Float16* __restrict__ pq, const float* __restrict__ ea,
    const int* __restrict__ ends, const int* __restrict__ perm,
    const int* __restrict__ srcp,
    const _Float16* __restrict__ w1cbG, const float* __restrict__ b1,
    const _Float16* __restrict__ w2h, const float* __restrict__ b2,
    float* __restrict__ hout, float* __restrict__ stats, int M)
{
    __shared__ __align__(16) _Float16 t1h[4 * QSL];    // 9.0 KB
    __shared__ __align__(16) _Float16 eash[4 * ESL];   // 5.0 KB
    __shared__ __align__(16) float ps[NPB * 68];       // 4.25 KB
    __shared__ __align__(16) unsigned rmu[NPB * 68];   // 4.25 KB
    __shared__ int endsL[NPB + 1];
    // total ~22.6 KB -> 6 blocks/CU (LDS-limited)

    const int t = threadIdx.x;
    const int lane = t & 63;
    const int wid = t >> 6;
    const int n0 = blockIdx.x * NPB;
    const int c = lane;
    const int quad = lane >> 4;
    const int col = lane & 15;
    const int ej = lane >> 2;    // local edge 0..15 (4 lanes per edge)
    const int j4 = lane & 3;

    if (t <= NPB) {
        int n = n0 + t - 1;
        endsL[t] = (t == 0) ? ((n0 == 0) ? 0 : ends[n0 - 1])
                            : ((n < M) ? ends[n] : ends[M - 1]);
    }
    for (int nn = wid; nn < NPB; nn += 4) {
        int node = n0 + nn;
        ps[nn * 68 + c] =
            ((node < M) ? (float)pq[(size_t)node * 128 + c] : 0.f) + b1[c];
    }
    for (int i = t; i < NPB * 68; i += 256) rmu[i] = 0u;   // 0 < enc(anything)

    half8 bfrag[4][2];
#pragma unroll
    for (int nt = 0; nt < 4; ++nt)
#pragma unroll
        for (int kc = 0; kc < 2; ++kc)
            bfrag[nt][kc] = *(const half8*)(w2h + ((nt * 2 + kc) * 64 + lane) * 8);
    half8 w1cb[4];
#pragma unroll
    for (int nt = 0; nt < 4; ++nt)
        w1cb[nt] = *(const half8*)(w1cbG + (nt * 64 + lane) * 8);

    __syncthreads();

    const int eBeg = endsL[0], eEnd = endsL[NPB];
    const int emax = (eEnd > 0) ? eEnd - 1 : 0;
    const int STEP = 4 * WED;                 // 64
    const int g0 = eBeg + wid * WED;          // this wave's first group

    _Float16* tsl = t1h + wid * QSL;          // private slices
    _Float16* esl = eash + wid * ESL;

    // per-wave prefetch state (16 VGPR): payload(g), indices(g+1)
    half8  qv0 = {}, qv1 = {};
    float4 eav = make_float4(0.f, 0.f, 0.f, 0.f);
    int sidN = 0, peN = 0;

    if (g0 < eEnd) {
        int g = min(g0 + ej, emax);
        int sid0 = srcp[g];
        int pe0  = perm[g];
        const _Float16* qs = pq + (size_t)sid0 * 128 + 64 + j4 * 16;
        qv0 = *(const half8*)(qs);
        qv1 = *(const half8*)(qs + 8);
        eav = *(const float4*)&ea[(size_t)pe0 * 16 + j4 * 4];
        int g2 = min(g0 + STEP + ej, emax);
        sidN = srcp[g2];
        peN  = perm[g2];
    }

    for (int gs = g0; gs < eEnd; gs += STEP) {
        // ---- 1. write payload(gs) into own slice (same-wave DS order) ----
        {
            _Float16* qd = tsl + ej * TSH + j4 * 16;
            *(half8*)qd = qv0;
            *(half8*)(qd + 8) = qv1;

            float xs[4] = { eav.x, eav.y, eav.z, eav.w };
            half4 hi4, lo4;
#pragma unroll
            for (int j = 0; j < 4; ++j) {
                _Float16 hj = (_Float16)xs[j];
                hi4[j] = hj;
                lo4[j] = (_Float16)(xs[j] - (float)hj);
            }
            _Float16* ed = esl + ej * EST + j4 * 4;
            *(half4*)ed = hi4;          // hi block: halfs [0,16)
            *(half4*)(ed + 16) = lo4;   // lo block: halfs [16,32)
        }

        // ---- 2. issue payload(gs+STEP); 3. issue idx(gs+2*STEP) ----
        if (gs + STEP < eEnd) {
            const _Float16* qs = pq + (size_t)sidN * 128 + 64 + j4 * 16;
            qv0 = *(const half8*)(qs);
            qv1 = *(const half8*)(qs + 8);
            eav = *(const float4*)&ea[(size_t)peN * 16 + j4 * 4];
            if (gs + 2 * STEP < eEnd) {
                int g2 = min(gs + 2 * STEP + ej, emax);
                sidN = srcp[g2];
                peN  = perm[g2];
            }
        }
        __builtin_amdgcn_sched_barrier(0);   // pin load issue before compute

        // ---- 4. lnod: lane computes its local edge's node, then shfl ----
        int Lv = 0;
        {
            int gp = gs + (lane & 15);
            int lo = 0, hi = NPB;
#pragma unroll
            for (int s = 0; s < 4; ++s) {
                int mid = (lo + hi) >> 1;
                bool geq = gp >= endsL[mid];
                lo = geq ? mid : lo;
                hi = geq ? hi : mid;
            }
            Lv = lo;
        }
        const int L0 = __shfl(Lv, quad * 4 + 0, 64);
        const int L1 = __shfl(Lv, quad * 4 + 1, 64);
        const int L2 = __shfl(Lv, quad * 4 + 2, 64);
        const int L3 = __shfl(Lv, quad * 4 + 3, 64);

        // ---- 5. C' : C-in = ps + q, += ea@w1c (MFMA), relu -> t1 ----
        _Float16* qb = tsl + (quad * 4) * TSH + col;
        const float* p0 = &ps[L0 * 68 + col];
        const float* p1 = &ps[L1 * 68 + col];
        const float* p2 = &ps[L2 * 68 + col];
        const float* p3 = &ps[L3 * 68 + col];
        floatx4 acc[4];
#pragma unroll
        for (int nt = 0; nt < 4; ++nt) {
            acc[nt][0] = (float)qb[0 * TSH + nt * 16] + p0[nt * 16];
            acc[nt][1] = (float)qb[1 * TSH + nt * 16] + p1[nt * 16];
            acc[nt][2] = (float)qb[2 * TSH + nt * 16] + p2[nt * 16];
            acc[nt][3] = (float)qb[3 * TSH + nt * 16] + p3[nt * 16];
        }
        half8 af = *(const half8*)&esl[col * EST + quad * 8];
#pragma unroll
        for (int nt = 0; nt < 4; ++nt)
            acc[nt] = __builtin_amdgcn_mfma_f32_16x16x32_f16(
                af, w1cb[nt], acc[nt], 0, 0, 0);
#pragma unroll
        for (int nt = 0; nt < 4; ++nt) {
#pragma unroll
            for (int r = 0; r < 4; ++r)
                qb[r * TSH + nt * 16] = (_Float16)fmaxf(acc[nt][r], 0.f);
        }

        // ---- 6. D : m = t1 @ w2 (MFMA), segmented max into rmu ----
        floatx4 accD[4] = {{0.f,0.f,0.f,0.f},{0.f,0.f,0.f,0.f},
                           {0.f,0.f,0.f,0.f},{0.f,0.f,0.f,0.f}};
#pragma unroll
        for (int kc = 0; kc < 2; ++kc) {
            half8 a = *(const half8*)&tsl[col * TSH + kc * 32 + quad * 8];
#pragma unroll
            for (int nt = 0; nt < 4; ++nt)
                accD[nt] = __builtin_amdgcn_mfma_f32_16x16x32_f16(
                    a, bfrag[nt][kc], accD[nt], 0, 0, 0);
        }
        const int gbase = gs + quad * 4;
#pragma unroll
        for (int nt = 0; nt < 4; ++nt) {
            int curL = -1;
            float best = 0.f;
#pragma unroll
            for (int r = 0; r < 4; ++r) {
                int ge = gbase + r;
                if (ge < eEnd) {
                    int L = (r == 0) ? L0 : (r == 1) ? L1
                          : (r == 2) ? L2 : L3;
                    float v = accD[nt][r];
                    if (L != curL) {
                        if (curL >= 0)
                            atomicMax(&rmu[curL * 68 + nt * 16 + col],
                                      enc(best));
                        curL = L; best = v;
                    } else best = fmaxf(best, v);
                }
            }
            if (curL >= 0)
                atomicMax(&rmu[curL * 68 + nt * 16 + col], enc(best));
        }
    }

    __syncthreads();   // all waves' rmu atomics done

    // ---- final store (+b2, raw agg; BN deferred to consumer) + BN stats ----
    for (int idx = t; idx < NPB * 64; idx += 256) {
        int L = idx >> 6, cc = idx & 63;
        int node = n0 + L;
        float v = 0.f;
        if (node < M) {
            if (endsL[L + 1] > endsL[L]) v = dec(rmu[L * 68 + cc]) + b2[cc];
            hout[(size_t)node * 64 + cc] = v;
        }
        ((float*)rmu)[L * 68 + cc] = v;   // own slot: no race
    }
    __syncthreads();
    if (t < 64) {
        float s = 0.f, s2 = 0.f;
#pragma unroll
        for (int L = 0; L < NPB; ++L) {
            float v = ((float*)rmu)[L * 68 + t];
            s += v;
            s2 = fmaf(v, v, s2);
        }
        atomicAdd(&stats[t], s);
        atomicAdd(&stats[64 + t], s2);
    }
}

// ---------------------------------------------------------------------------
extern "C" void kernel_launch(void* const* d_in, const int* in_sizes, int n_in,
                              void* d_out, int out_size, void* d_ws, size_t ws_size,
                              hipStream_t stream)
{
    const float* x     = (const float*)d_in[0];
    const int*   eidx  = (const int*)  d_in[1];
    const float* ea    = (const float*)d_in[2];
    const float* w_in  = (const float*)d_in[3];
    const float* b_in  = (const float*)d_in[4];
    const float* w1    = (const float*)d_in[5];
    const float* b1    = (const float*)d_in[6];
    const float* w2    = (const float*)d_in[7];
    const float* b2    = (const float*)d_in[8];
    const float* gamma = (const float*)d_in[9];
    const float* beta  = (const float*)d_in[10];
    const float* w_m1  = (const float*)d_in[11];
    const float* b_m1  = (const float*)d_in[12];
    const float* w_m2  = (const float*)d_in[13];
    const float* b_m2  = (const float*)d_in[14];

    const int M = in_sizes[0] / 64;   // n_nodes
    const int E = in_sizes[1] / 2;    // n_edges
    const int* src = eidx;            // edge_index[0]
    const int* tgt = eidx + E;        // edge_index[1] (aggregation target)

    // ws: hagg f32 | pqh f16 | ends | srcp | part | stats = 29.0 MB
    float* hagg   = (float*)d_ws;
    _Float16* pqh = (_Float16*)(hagg + (size_t)M * 64);
    int* ends     = (int*)(pqh + (size_t)M * 128);
    int* srcp     = ends + M;
    const int nb  = (M + 255) / 256;
    int* part     = srcp + E;
    float* stats  = (float*)(part + nb);
    // d_out scratch: perm[E] | w2h | w1ch — dead before head writes d_out
    int* perm = (int*)d_out;
    _Float16* w2h  = (_Float16*)((char*)d_out + (size_t)E * 4);
    _Float16* w1ch = (_Float16*)((char*)d_out + (size_t)E * 4 + 16384);

    dim3 blk(256);
    const int gm64 = (M + 63) / 64;
    const int gE   = (E + 255) / 256;

    // CSR build + weight pack (+stats zero)
    (void)hipMemsetAsync(ends, 0, (size_t)M * 4, stream);
    hist_tgt<<<gE, blk, 0, stream>>>(tgt, ends, E);
    scan_partial<<<nb, blk, 0, stream>>>(ends, part, M);
    scan_part2<<<1, blk, 0, stream>>>(part, nb);
    scan_add<<<nb, blk, 0, stream>>>(ends, part, M);
    fill_csr<<<gE, blk, 0, stream>>>(tgt, src, ends, perm, srcp, E);
    pack_w2<<<6, blk, 0, stream>>>(w2, w1, w2h, w1ch, stats);

    // h0 = relu(x @ w_in + b_in)
    gemm_h0<<<gm64, blk, 0, stream>>>(x, w_in, b_in, hagg, M);

    for (int l = 0; l < 2; ++l) {
        const float* w1l = w1 + (size_t)l * 144 * 64;
        if (l == 0)
            gemm_pq<false><<<gm64, blk, 0, stream>>>(hagg, w1l, pqh,
                nullptr, nullptr, nullptr, M);
        else
            gemm_pq<true><<<gm64, blk, 0, stream>>>(hagg, w1l, pqh,
                stats, gamma, beta, M);
        node_agg<<<(M + NPB - 1) / NPB, blk, 0, stream>>>(pqh, ea,
            ends, perm, srcp,
            w1ch + (size_t)l * 2048, b1 + l * 64,
            w2h + (size_t)l * 4096, b2 + l * 64,
            hagg, stats + l * 128, M);
    }

    // out = relu(BN1(h) @ w_m1 + b_m1) @ w_m2 + b_m2
    head_fused<<<gm64, blk, 0, stream>>>(hagg, stats + 128, gamma + 64, beta + 64,
        w_m1, b_m1, w_m2, b_m2, (float*)d_out, M);
}

// Round 10
// 521.217 us; speedup vs baseline: 1.0249x; 1.0249x over previous
//
#include <hip/hip_runtime.h>
#include <float.h>

// ---------------------------------------------------------------------------
// MPNN forward.  msg@w1 decomposed: per-node p=h@w1a, q=h@w1b (fused gemm_pq,
// f16 out, BN fused on A-load), per-edge ea@w1c; edge GEMM t1@w2 f16 MFMA.
// R20 == R19 resubmit (container acquisition failed twice; no kernel verdict).
// R19: attack the untouched ~278us outside node_agg (52% of total):
//  (1) gemm_h0 fused into gemm_pq<H0> (h0 was single-consumer: 12.8MB write +
//      12.8MB read + a launch for nothing; h-tile computed in-LDS, w_in
//      overlays Ws so LDS stays 49KB);
//  (2) scan_part2 (1-block kernel, whole-GPU idle) folded into scan_add2
//      (each block reduces part[0..bid) itself, nb=196<=256);
//  (3) pack_w2 fused into hist_pack (independent work, shared launch).
// node_agg: R18 barrier-free per-wave pipeline kept EXACTLY (best measured:
// 127.6us; 5 structural rewrites all land 127-136 -> pinned, moved on).
//
// ws (proven bound 38,601,024 B): hagg 12.8M | pqh 12.8M | ends 200K |
//   srcp 3.2M | part | stats(256f)  = 29.0 MB.
// d_out scratch: perm 3.2M | w2h 16K | w1ch 8K (dead before head writes).
// ---------------------------------------------------------------------------

typedef _Float16 half8 __attribute__((ext_vector_type(8)));
typedef _Float16 half4 __attribute__((ext_vector_type(4)));
typedef float floatx4 __attribute__((ext_vector_type(4)));

#define BN_EPS 1e-5f

__device__ __forceinline__ unsigned enc(float f) {
    unsigned u = __float_as_uint(f);
    return (u & 0x80000000u) ? ~u : (u | 0x80000000u);
}
__device__ __forceinline__ float dec(unsigned u) {
    return (u & 0x80000000u) ? __uint_as_float(u & 0x7fffffffu)
                             : __uint_as_float(~u);
}

// ---------------------------------------------------------------------------
// Fused p|q GEMM, f16 out.  H0: first compute A=relu(x@w_in+b_in) in-LDS
// (identical math to the old gemm_h0).  BN: BN+relu fused on A-load.
// ---------------------------------------------------------------------------
template<bool H0, bool BN>
__global__ __launch_bounds__(256) void gemm_pq(
    const float* __restrict__ A, const float* __restrict__ W,
    const float* __restrict__ Wh0, const float* __restrict__ bh0,
    _Float16* __restrict__ PQ, const float* __restrict__ stats,
    const float* __restrict__ gamma, const float* __restrict__ beta, int M)
{
    __shared__ __align__(16) float Ws[64 * 128];
    __shared__ __align__(16) float As[64 * 68];

    const int t = threadIdx.x;
    const int m0 = blockIdx.x * 64;

    if (H0) {
        // ---- stage w_in (overlays Ws[0:4096]) + x tile ----
        for (int i = t; i < 64 * 64; i += 256) Ws[i] = Wh0[i];
        for (int rr = 0; rr < 64; rr += 16) {
            int r = rr + (t >> 4);
            int c4 = (t & 15) * 4;
            int row = m0 + r;
            float4 v = make_float4(0.f, 0.f, 0.f, 0.f);
            if (row < M) v = *(const float4*)&A[(size_t)row * 64 + c4];
            *(float4*)&As[r * 68 + c4] = v;
        }
        __syncthreads();

        // ---- h = relu(x @ w_in + b_in), same layout as old gemm_h0 ----
        const int tc = t & 15, tr = t >> 4;
        float4 hacc[4];
        float4 bv = *(const float4*)&bh0[tc * 4];
#pragma unroll
        for (int i = 0; i < 4; ++i) hacc[i] = bv;
#pragma unroll 8
        for (int k = 0; k < 64; ++k) {
            float4 w = *(const float4*)&Ws[k * 64 + tc * 4];
#pragma unroll
            for (int i = 0; i < 4; ++i) {
                float a = As[(tr + i * 16) * 68 + k];
                hacc[i].x = fmaf(a, w.x, hacc[i].x);
                hacc[i].y = fmaf(a, w.y, hacc[i].y);
                hacc[i].z = fmaf(a, w.z, hacc[i].z);
                hacc[i].w = fmaf(a, w.w, hacc[i].w);
            }
        }
        __syncthreads();   // all reads of As/Ws done before overwrite

        // ---- write relu(h) back into As; stage W=[w1a|w1b] over Ws ----
#pragma unroll
        for (int i = 0; i < 4; ++i) {
            float4 o = hacc[i];
            o.x = fmaxf(o.x, 0.f); o.y = fmaxf(o.y, 0.f);
            o.z = fmaxf(o.z, 0.f); o.w = fmaxf(o.w, 0.f);
            *(float4*)&As[(tr + i * 16) * 68 + tc * 4] = o;
        }
        for (int i = t; i < 64 * 128; i += 256) {
            int k = i >> 7, n = i & 127;
            Ws[i] = W[(size_t)((n < 64 ? k : 64 + k)) * 64 + (n & 63)];
        }
        __syncthreads();
    } else {
        for (int i = t; i < 64 * 128; i += 256) {
            int k = i >> 7, n = i & 127;
            Ws[i] = W[(size_t)((n < 64 ? k : 64 + k)) * 64 + (n & 63)];
        }
        {
            int c4 = (t & 15) * 4;
            float sc[4], sh[4];
            if (BN) {
                float invM = 1.f / (float)M;
#pragma unroll
                for (int j = 0; j < 4; ++j) {
                    int c = c4 + j;
                    float mu = stats[c] * invM;
                    float var = fmaxf(stats[64 + c] * invM - mu * mu, 0.f);
                    float s = gamma[c] * rsqrtf(var + BN_EPS);
                    sc[j] = s; sh[j] = beta[c] - mu * s;
                }
            }
            for (int rr = 0; rr < 64; rr += 16) {
                int r = rr + (t >> 4);
                int row = m0 + r;
                float4 v = make_float4(0.f, 0.f, 0.f, 0.f);
                if (row < M) v = *(const float4*)&A[(size_t)row * 64 + c4];
                if (BN) {
                    v.x = fmaxf(fmaf(v.x, sc[0], sh[0]), 0.f);
                    v.y = fmaxf(fmaf(v.y, sc[1], sh[1]), 0.f);
                    v.z = fmaxf(fmaf(v.z, sc[2], sh[2]), 0.f);
                    v.w = fmaxf(fmaf(v.w, sc[3], sh[3]), 0.f);
                }
                *(float4*)&As[r * 68 + c4] = v;
            }
        }
        __syncthreads();
    }

    const int tc = t & 31, tr = t >> 5;
    float4 acc[8];
#pragma unroll
    for (int i = 0; i < 8; ++i) acc[i] = make_float4(0.f, 0.f, 0.f, 0.f);
#pragma unroll 8
    for (int k = 0; k < 64; ++k) {
        float4 w = *(const float4*)&Ws[k * 128 + tc * 4];
#pragma unroll
        for (int i = 0; i < 8; ++i) {
            float a = As[(tr + i * 8) * 68 + k];
            acc[i].x = fmaf(a, w.x, acc[i].x);
            acc[i].y = fmaf(a, w.y, acc[i].y);
            acc[i].z = fmaf(a, w.z, acc[i].z);
            acc[i].w = fmaf(a, w.w, acc[i].w);
        }
    }
#pragma unroll
    for (int i = 0; i < 8; ++i) {
        int row = m0 + tr + i * 8;
        if (row < M) {
            half4 o = { (_Float16)acc[i].x, (_Float16)acc[i].y,
                        (_Float16)acc[i].z, (_Float16)acc[i].w };
            *(half4*)&PQ[(size_t)row * 128 + tc * 4] = o;
        }
    }
}

// ---------------------------------------------------------------------------
// Fused head: out = relu(BN(h) @ w_m1 + b_m1) @ w_m2 + b_m2
// ---------------------------------------------------------------------------
__global__ __launch_bounds__(256) void head_fused(
    const float* __restrict__ hagg, const float* __restrict__ stats,
    const float* __restrict__ gamma, const float* __restrict__ beta,
    const float* __restrict__ w_m1, const float* __restrict__ b_m1,
    const float* __restrict__ w_m2, const float* __restrict__ b_m2,
    float* __restrict__ out, int M)
{
    __shared__ __align__(16) float Ws1[64 * 64];
    __shared__ __align__(16) float Ws2[64 * 32];
    __shared__ __align__(16) float As[64 * 68];
    __shared__ __align__(16) float Ts[64 * 68];

    const int t = threadIdx.x;
    const int m0 = blockIdx.x * 64;

    for (int i = t; i < 64 * 64; i += 256) Ws1[i] = w_m1[i];
    for (int i = t; i < 64 * 32; i += 256) Ws2[i] = w_m2[i];
    {
        int c4 = (t & 15) * 4;
        float sc[4], sh[4];
        float invM = 1.f / (float)M;
#pragma unroll
        for (int j = 0; j < 4; ++j) {
            int c = c4 + j;
            float mu = stats[c] * invM;
            float var = fmaxf(stats[64 + c] * invM - mu * mu, 0.f);
            float s = gamma[c] * rsqrtf(var + BN_EPS);
            sc[j] = s; sh[j] = beta[c] - mu * s;
        }
        for (int rr = 0; rr < 64; rr += 16) {
            int r = rr + (t >> 4);
            int row = m0 + r;
            float4 v = make_float4(0.f, 0.f, 0.f, 0.f);
            if (row < M) v = *(const float4*)&hagg[(size_t)row * 64 + c4];
            v.x = fmaxf(fmaf(v.x, sc[0], sh[0]), 0.f);
            v.y = fmaxf(fmaf(v.y, sc[1], sh[1]), 0.f);
            v.z = fmaxf(fmaf(v.z, sc[2], sh[2]), 0.f);
            v.w = fmaxf(fmaf(v.w, sc[3], sh[3]), 0.f);
            *(float4*)&As[r * 68 + c4] = v;
        }
    }
    __syncthreads();

    {
        const int tc = t & 15, tr = t >> 4;
        float4 acc[4];
        float4 bv = *(const float4*)&b_m1[tc * 4];
#pragma unroll
        for (int i = 0; i < 4; ++i) acc[i] = bv;
#pragma unroll 8
        for (int k = 0; k < 64; ++k) {
            float4 w = *(const float4*)&Ws1[k * 64 + tc * 4];
#pragma unroll
            for (int i = 0; i < 4; ++i) {
                float a = As[(tr + i * 16) * 68 + k];
                acc[i].x = fmaf(a, w.x, acc[i].x);
                acc[i].y = fmaf(a, w.y, acc[i].y);
                acc[i].z = fmaf(a, w.z, acc[i].z);
                acc[i].w = fmaf(a, w.w, acc[i].w);
            }
        }
#pragma unroll
        for (int i = 0; i < 4; ++i) {
            float4 o = acc[i];
            o.x = fmaxf(o.x, 0.f); o.y = fmaxf(o.y, 0.f);
            o.z = fmaxf(o.z, 0.f); o.w = fmaxf(o.w, 0.f);
            *(float4*)&Ts[(tr + i * 16) * 68 + tc * 4] = o;
        }
    }
    __syncthreads();

    {
        const int tc = t & 7, tr = t >> 3;
        float4 acc[2];
        float4 bv = *(const float4*)&b_m2[tc * 4];
        acc[0] = bv; acc[1] = bv;
#pragma unroll 8
        for (int k = 0; k < 64; ++k) {
            float4 w = *(const float4*)&Ws2[k * 32 + tc * 4];
#pragma unroll
            for (int i = 0; i < 2; ++i) {
                float a = Ts[(tr + i * 32) * 68 + k];
                acc[i].x = fmaf(a, w.x, acc[i].x);
                acc[i].y = fmaf(a, w.y, acc[i].y);
                acc[i].z = fmaf(a, w.z, acc[i].z);
                acc[i].w = fmaf(a, w.w, acc[i].w);
            }
        }
#pragma unroll
        for (int i = 0; i < 2; ++i) {
            int row = m0 + tr + i * 32;
            if (row < M) *(float4*)&out[(size_t)row * 32 + tc * 4] = acc[i];
        }
    }
}

// ---------------------------------------------------------------------------
// CSR build: hist(+pack fused) -> scan_partial -> scan_add2 -> fill
// ---------------------------------------------------------------------------
__global__ __launch_bounds__(256) void hist_pack(const int* __restrict__ tgt,
    int* __restrict__ cnt, int E,
    const float* __restrict__ w2, const float* __restrict__ w1,
    _Float16* __restrict__ w2h, _Float16* __restrict__ w1ch,
    float* __restrict__ stats)
{
    const int gE = (E + 255) >> 8;
    const int b = blockIdx.x;
    if (b < gE) {
        int e = b * 256 + threadIdx.x;
        if (e < E) atomicAdd(&cnt[tgt[e]], 1);
        return;
    }
    int id = (b - gE) * 256 + threadIdx.x;
    if (id < 256) stats[id] = 0.f;
    if (id < 1024) {
        int l = id >> 9, rem = id & 511;
        int frag = rem >> 6, lane = rem & 63;
        int nt = frag >> 1, kc = frag & 1;
        const float* W = w2 + (size_t)l * 4096;
        _Float16* O = w2h + (size_t)l * 4096 + (frag * 64 + lane) * 8;
        int n = nt * 16 + (lane & 15);
        int k0 = kc * 32 + (lane >> 4) * 8;
#pragma unroll
        for (int j = 0; j < 8; ++j) O[j] = (_Float16)W[(k0 + j) * 64 + n];
    } else if (id < 1536) {
        // w1ch: B[k][n] = w1c[k & 15][n], K=32 (duplicated halves), 4 nt tiles
        int rem2 = id - 1024;
        int l = rem2 >> 8, rem = rem2 & 255;
        int nt = rem >> 6, lane = rem & 63;
        const float* W1C = w1 + (size_t)l * 144 * 64 + 128 * 64;
        _Float16* O = w1ch + (size_t)l * 2048 + (nt * 64 + lane) * 8;
        int n = nt * 16 + (lane & 15);
        int k0 = (lane >> 4) * 8;
#pragma unroll
        for (int j = 0; j < 8; ++j)
            O[j] = (_Float16)W1C[((k0 + j) & 15) * 64 + n];
    }
}

__global__ __launch_bounds__(256) void scan_partial(const int* __restrict__ cnt,
                                                    int* __restrict__ part, int M)
{
    __shared__ int s[256];
    int i = blockIdx.x * 256 + threadIdx.x;
    s[threadIdx.x] = (i < M) ? cnt[i] : 0;
    __syncthreads();
    for (int off = 128; off > 0; off >>= 1) {
        if (threadIdx.x < off) s[threadIdx.x] += s[threadIdx.x + off];
        __syncthreads();
    }
    if (threadIdx.x == 0) part[blockIdx.x] = s[0];
}

// scan_add2: block computes its own prefix offset (sum part[0..bid)), then
// in-block exclusive scan of cnt.  Replaces scan_part2 + scan_add.
__global__ __launch_bounds__(256) void scan_add2(int* __restrict__ cnt,
    const int* __restrict__ part, int M, int nb)
{
    __shared__ int s[256];
    const int t = threadIdx.x;
    const int bid = blockIdx.x;

    int v0 = (t < bid && t < nb) ? part[t] : 0;
    s[t] = v0;
    __syncthreads();
    for (int off = 128; off > 0; off >>= 1) {
        if (t < off) s[t] += s[t + off];
        __syncthreads();
    }
    const int base = s[0];
    __syncthreads();

    int i = bid * 256 + t;
    int v = (i < M) ? cnt[i] : 0;
    s[t] = v;
    __syncthreads();
    for (int off = 1; off < 256; off <<= 1) {
        int a = (t >= off) ? s[t - off] : 0;
        __syncthreads();
        s[t] += a;
        __syncthreads();
    }
    if (i < M) cnt[i] = base + s[t] - v;   // exclusive
}

__global__ __launch_bounds__(256) void fill_csr(const int* __restrict__ tgt,
    const int* __restrict__ src, int* __restrict__ arr,
    int* __restrict__ perm, int* __restrict__ srcp, int E)
{
    int e = blockIdx.x * 256 + threadIdx.x;
    if (e < E) {
        int pos = atomicAdd(&arr[tgt[e]], 1);
        perm[pos] = e;
        srcp[pos] = src[e];
    }
}

// ---------------------------------------------------------------------------
// Fused per-node edge-MLP + segmented max + BN stats.
//   R18: barrier-free per-wave micro-tile pipeline (16 edges/group, private
//   LDS slice per wave, no __syncthreads in main loop).  ea@w1c via MFMA
//   (exact hi/lo split), C'+D fused, lnod via binary search + shfl.
// ---------------------------------------------------------------------------
#define NPB 16
#define WED 16     // edges per wave micro-tile
#define TSH 72     // t1/q stride in halfs (144 B -> 2-way b128, free)
#define EST 40     // eash stride in halfs (80 B, 16B-aligned rows, 2-way)
#define QSL (WED * TSH)   // 1152 halfs per wave slice
#define ESL (WED * EST)   //  640 halfs per wave slice

__global__ __launch_bounds__(256, 4) void node_agg(
    const _Float16* __restrict__ pq, const float* __restrict__ ea,
    const int* __restrict__ ends, const int* __restrict__ perm,
    const int* __restrict__ srcp,
    const _Float16* __restrict__ w1cbG, const float* __restrict__ b1,
    const _Float16* __restrict__ w2h, const float* __restrict__ b2,
    float* __restrict__ hout, float* __restrict__ stats, int M)
{
    __shared__ __align__(16) _Float16 t1h[4 * QSL];    // 9.0 KB
    __shared__ __align__(16) _Float16 eash[4 * ESL];   // 5.0 KB
    __shared__ __align__(16) float ps[NPB * 68];       // 4.25 KB
    __shared__ __align__(16) unsigned rmu[NPB * 68];   // 4.25 KB
    __shared__ int endsL[NPB + 1];
    // total ~22.6 KB -> 6 blocks/CU (LDS-limited)

    const int t = threadIdx.x;
    const int lane = t & 63;
    const int wid = t >> 6;
    const int n0 = blockIdx.x * NPB;
    const int c = lane;
    const int quad = lane >> 4;
    const int col = lane & 15;
    const int ej = lane >> 2;    // local edge 0..15 (4 lanes per edge)
    const int j4 = lane & 3;

    if (t <= NPB) {
        int n = n0 + t - 1;
        endsL[t] = (t == 0) ? ((n0 == 0) ? 0 : ends[n0 - 1])
                            : ((n < M) ? ends[n] : ends[M - 1]);
    }
    for (int nn = wid; nn < NPB; nn += 4) {
        int node = n0 + nn;
        ps[nn * 68 + c] =
            ((node < M) ? (float)pq[(size_t)node * 128 + c] : 0.f) + b1[c];
    }
    for (int i = t; i < NPB * 68; i += 256) rmu[i] = 0u;   // 0 < enc(anything)

    half8 bfrag[4][2];
#pragma unroll
    for (int nt = 0; nt < 4; ++nt)
#pragma unroll
        for (int kc = 0; kc < 2; ++kc)
            bfrag[nt][kc] = *(const half8*)(w2h + ((nt * 2 + kc) * 64 + lane) * 8);
    half8 w1cb[4];
#pragma unroll
    for (int nt = 0; nt < 4; ++nt)
        w1cb[nt] = *(const half8*)(w1cbG + (nt * 64 + lane) * 8);

    __syncthreads();

    const int eBeg = endsL[0], eEnd = endsL[NPB];
    const int emax = (eEnd > 0) ? eEnd - 1 : 0;
    const int STEP = 4 * WED;                 // 64
    const int g0 = eBeg + wid * WED;          // this wave's first group

    _Float16* tsl = t1h + wid * QSL;          // private slices
    _Float16* esl = eash + wid * ESL;

    // per-wave prefetch state (16 VGPR): payload(g), indices(g+1)
    half8  qv0 = {}, qv1 = {};
    float4 eav = make_float4(0.f, 0.f, 0.f, 0.f);
    int sidN = 0, peN = 0;

    if (g0 < eEnd) {
        int g = min(g0 + ej, emax);
        int sid0 = srcp[g];
        int pe0  = perm[g];
        const _Float16* qs = pq + (size_t)sid0 * 128 + 64 + j4 * 16;
        qv0 = *(const half8*)(qs);
        qv1 = *(const half8*)(qs + 8);
        eav = *(const float4*)&ea[(size_t)pe0 * 16 + j4 * 4];
        int g2 = min(g0 + STEP + ej, emax);
        sidN = srcp[g2];
        peN  = perm[g2];
    }

    for (int gs = g0; gs < eEnd; gs += STEP) {
        // ---- 1. write payload(gs) into own slice (same-wave DS order) ----
        {
            _Float16* qd = tsl + ej * TSH + j4 * 16;
            *(half8*)qd = qv0;
            *(half8*)(qd + 8) = qv1;

            float xs[4] = { eav.x, eav.y, eav.z, eav.w };
            half4 hi4, lo4;
#pragma unroll
            for (int j = 0; j < 4; ++j) {
                _Float16 hj = (_Float16)xs[j];
                hi4[j] = hj;
                lo4[j] = (_Float16)(xs[j] - (float)hj);
            }
            _Float16* ed = esl + ej * EST + j4 * 4;
            *(half4*)ed = hi4;          // hi block: halfs [0,16)
            *(half4*)(ed + 16) = lo4;   // lo block: halfs [16,32)
        }

        // ---- 2. issue payload(gs+STEP); 3. issue idx(gs+2*STEP) ----
        if (gs + STEP < eEnd) {
            const _Float16* qs = pq + (size_t)sidN * 128 + 64 + j4 * 16;
            qv0 = *(const half8*)(qs);
            qv1 = *(const half8*)(qs + 8);
            eav = *(const float4*)&ea[(size_t)peN * 16 + j4 * 4];
            if (gs + 2 * STEP < eEnd) {
                int g2 = min(gs + 2 * STEP + ej, emax);
                sidN = srcp[g2];
                peN  = perm[g2];
            }
        }
        __builtin_amdgcn_sched_barrier(0);   // pin load issue before compute

        // ---- 4. lnod: lane computes its local edge's node, then shfl ----
        int Lv = 0;
        {
            int gp = gs + (lane & 15);
            int lo = 0, hi = NPB;
#pragma unroll
            for (int s = 0; s < 4; ++s) {
                int mid = (lo + hi) >> 1;
                bool geq = gp >= endsL[mid];
                lo = geq ? mid : lo;
                hi = geq ? hi : mid;
            }
            Lv = lo;
        }
        const int L0 = __shfl(Lv, quad * 4 + 0, 64);
        const int L1 = __shfl(Lv, quad * 4 + 1, 64);
        const int L2 = __shfl(Lv, quad * 4 + 2, 64);
        const int L3 = __shfl(Lv, quad * 4 + 3, 64);

        // ---- 5. C' : C-in = ps + q, += ea@w1c (MFMA), relu -> t1 ----
        _Float16* qb = tsl + (quad * 4) * TSH + col;
        const float* p0 = &ps[L0 * 68 + col];
        const float* p1 = &ps[L1 * 68 + col];
        const float* p2 = &ps[L2 * 68 + col];
        const float* p3 = &ps[L3 * 68 + col];
        floatx4 acc[4];
#pragma unroll
        for (int nt = 0; nt < 4; ++nt) {
            acc[nt][0] = (float)qb[0 * TSH + nt * 16] + p0[nt * 16];
            acc[nt][1] = (float)qb[1 * TSH + nt * 16] + p1[nt * 16];
            acc[nt][2] = (float)qb[2 * TSH + nt * 16] + p2[nt * 16];
            acc[nt][3] = (float)qb[3 * TSH + nt * 16] + p3[nt * 16];
        }
        half8 af = *(const half8*)&esl[col * EST + quad * 8];
#pragma unroll
        for (int nt = 0; nt < 4; ++nt)
            acc[nt] = __builtin_amdgcn_mfma_f32_16x16x32_f16(
                af, w1cb[nt], acc[nt], 0, 0, 0);
#pragma unroll
        for (int nt = 0; nt < 4; ++nt) {
#pragma unroll
            for (int r = 0; r < 4; ++r)
                qb[r * TSH + nt * 16] = (_Float16)fmaxf(acc[nt][r], 0.f);
        }

        // ---- 6. D : m = t1 @ w2 (MFMA), segmented max into rmu ----
        floatx4 accD[4] = {{0.f,0.f,0.f,0.f},{0.f,0.f,0.f,0.f},
                           {0.f,0.f,0.f,0.f},{0.f,0.f,0.f,0.f}};
#pragma unroll
        for (int kc = 0; kc < 2; ++kc) {
            half8 a = *(const half8*)&tsl[col * TSH + kc * 32 + quad * 8];
#pragma unroll
            for (int nt = 0; nt < 4; ++nt)
                accD[nt] = __builtin_amdgcn_mfma_f32_16x16x32_f16(
                    a, bfrag[nt][kc], accD[nt], 0, 0, 0);
        }
        const int gbase = gs + quad * 4;
#pragma unroll
        for (int nt = 0; nt < 4; ++nt) {
            int curL = -1;
            float best = 0.f;
#pragma unroll
            for (int r = 0; r < 4; ++r) {
                int ge = gbase + r;
                if (ge < eEnd) {
                    int L = (r == 0) ? L0 : (r == 1) ? L1
                          : (r == 2) ? L2 : L3;
                    float v = accD[nt][r];
                    if (L != curL) {
                        if (curL >= 0)
                            atomicMax(&rmu[curL * 68 + nt * 16 + col],
                                      enc(best));
                        curL = L; best = v;
                    } else best = fmaxf(best, v);
                }
            }
            if (curL >= 0)
                atomicMax(&rmu[curL * 68 + nt * 16 + col], enc(best));
        }
    }

    __syncthreads();   // all waves' rmu atomics done

    // ---- final store (+b2, raw agg; BN deferred to consumer) + BN stats ----
    for (int idx = t; idx < NPB * 64; idx += 256) {
        int L = idx >> 6, cc = idx & 63;
        int node = n0 + L;
        float v = 0.f;
        if (node < M) {
            if (endsL[L + 1] > endsL[L]) v = dec(rmu[L * 68 + cc]) + b2[cc];
            hout[(size_t)node * 64 + cc] = v;
        }
        ((float*)rmu)[L * 68 + cc] = v;   // own slot: no race
    }
    __syncthreads();
    if (t < 64) {
        float s = 0.f, s2 = 0.f;
#pragma unroll
        for (int L = 0; L < NPB; ++L) {
            float v = ((float*)rmu)[L * 68 + t];
            s += v;
            s2 = fmaf(v, v, s2);
        }
        atomicAdd(&stats[t], s);
        atomicAdd(&stats[64 + t], s2);
    }
}

// ---------------------------------------------------------------------------
extern "C" void kernel_launch(void* const* d_in, const int* in_sizes, int n_in,
                              void* d_out, int out_size, void* d_ws, size_t ws_size,
                              hipStream_t stream)
{
    const float* x     = (const float*)d_in[0];
    const int*   eidx  = (const int*)  d_in[1];
    const float* ea    = (const float*)d_in[2];
    const float* w_in  = (const float*)d_in[3];
    const float* b_in  = (const float*)d_in[4];
    const float* w1    = (const float*)d_in[5];
    const float* b1    = (const float*)d_in[6];
    const float* w2    = (const float*)d_in[7];
    const float* b2    = (const float*)d_in[8];
    const float* gamma = (const float*)d_in[9];
    const float* beta  = (const float*)d_in[10];
    const float* w_m1  = (const float*)d_in[11];
    const float* b_m1  = (const float*)d_in[12];
    const float* w_m2  = (const float*)d_in[13];
    const float* b_m2  = (const float*)d_in[14];

    const int M = in_sizes[0] / 64;   // n_nodes
    const int E = in_sizes[1] / 2;    // n_edges
    const int* src = eidx;            // edge_index[0]
    const int* tgt = eidx + E;        // edge_index[1] (aggregation target)

    // ws: hagg f32 | pqh f16 | ends | srcp | part | stats = 29.0 MB
    float* hagg   = (float*)d_ws;
    _Float16* pqh = (_Float16*)(hagg + (size_t)M * 64);
    int* ends     = (int*)(pqh + (size_t)M * 128);
    int* srcp     = ends + M;
    const int nb  = (M + 255) / 256;
    int* part     = srcp + E;
    float* stats  = (float*)(part + nb);
    // d_out scratch: perm[E] | w2h | w1ch — dead before head writes d_out
    int* perm = (int*)d_out;
    _Float16* w2h  = (_Float16*)((char*)d_out + (size_t)E * 4);
    _Float16* w1ch = (_Float16*)((char*)d_out + (size_t)E * 4 + 16384);

    dim3 blk(256);
    const int gm64 = (M + 63) / 64;
    const int gE   = (E + 255) / 256;

    // CSR build + weight pack (+stats zero); scan_part2 folded into scan_add2
    (void)hipMemsetAsync(ends, 0, (size_t)M * 4, stream);
    hist_pack<<<gE + 6, blk, 0, stream>>>(tgt, ends, E, w2, w1, w2h, w1ch, stats);
    scan_partial<<<nb, blk, 0, stream>>>(ends, part, M);
    scan_add2<<<nb, blk, 0, stream>>>(ends, part, M, nb);
    fill_csr<<<gE, blk, 0, stream>>>(tgt, src, ends, perm, srcp, E);

    for (int l = 0; l < 2; ++l) {
        const float* w1l = w1 + (size_t)l * 144 * 64;
        if (l == 0)
            gemm_pq<true, false><<<gm64, blk, 0, stream>>>(x, w1l, w_in, b_in,
                pqh, nullptr, nullptr, nullptr, M);
        else
            gemm_pq<false, true><<<gm64, blk, 0, stream>>>(hagg, w1l,
                nullptr, nullptr, pqh, stats, gamma, beta, M);
        node_agg<<<(M + NPB - 1) / NPB, blk, 0, stream>>>(pqh, ea,
            ends, perm, srcp,
            w1ch + (size_t)l * 2048, b1 + l * 64,
            w2h + (size_t)l * 4096, b2 + l * 64,
            hagg, stats + l * 128, M);
    }

    // out = relu(BN1(h) @ w_m1 + b_m1) @ w_m2 + b_m2
    head_fused<<<gm64, blk, 0, stream>>>(hagg, stats + 128, gamma + 64, beta + 64,
        w_m1, b_m1, w_m2, b_m2, (float*)d_out, M);
}

// Round 11
// 479.806 us; speedup vs baseline: 1.1134x; 1.0863x over previous
//
#include <hip/hip_runtime.h>
#include <float.h>

// ---------------------------------------------------------------------------
// MPNN forward.  msg@w1 decomposed: per-node p=h@w1a, q=h@w1b (fused gemm_pq,
// f16 out, BN fused on A-load), per-edge ea@w1c; edge GEMM t1@w2 f16 MFMA.
// R21: de-atomize the CSR build.  hist's atomicAdd return (was discarded) is
// the within-node rank -> stored in within[e]; fill becomes atomic-free:
// pos = starts[tgt] + within[e], writing ONE int2 {src,e} (epair) instead of
// two 4B stores to arrays 3.2MB apart (halves scattered line touches).
// Scan result stays unmutated -> node_agg reads clean starts[] + E sentinel.
// node_agg: R18 barrier-free per-wave pipeline kept (pinned at ~127us over
// 5 rewrites); only its index load changed (one 8B epair broadcast).
// R19/R20: gemm_h0 fused into gemm_pq<H0>; scan_part2 folded into scan_add2;
// pack fused into hist_pack.
//
// ws: hagg 12.8M | pqh 12.8M | starts 200K | epair 6.4M | within 3.2M |
//   part | stats(256f) = 35.6 MB  (proven bound 38.6 MB).
// d_out scratch: w2h 16K | w1ch 8K (dead before head writes d_out).
// ---------------------------------------------------------------------------

typedef _Float16 half8 __attribute__((ext_vector_type(8)));
typedef _Float16 half4 __attribute__((ext_vector_type(4)));
typedef float floatx4 __attribute__((ext_vector_type(4)));

#define BN_EPS 1e-5f

__device__ __forceinline__ unsigned enc(float f) {
    unsigned u = __float_as_uint(f);
    return (u & 0x80000000u) ? ~u : (u | 0x80000000u);
}
__device__ __forceinline__ float dec(unsigned u) {
    return (u & 0x80000000u) ? __uint_as_float(u & 0x7fffffffu)
                             : __uint_as_float(~u);
}

// ---------------------------------------------------------------------------
// Fused p|q GEMM, f16 out.  H0: first compute A=relu(x@w_in+b_in) in-LDS
// (identical math to the old gemm_h0).  BN: BN+relu fused on A-load.
// ---------------------------------------------------------------------------
template<bool H0, bool BN>
__global__ __launch_bounds__(256) void gemm_pq(
    const float* __restrict__ A, const float* __restrict__ W,
    const float* __restrict__ Wh0, const float* __restrict__ bh0,
    _Float16* __restrict__ PQ, const float* __restrict__ stats,
    const float* __restrict__ gamma, const float* __restrict__ beta, int M)
{
    __shared__ __align__(16) float Ws[64 * 128];
    __shared__ __align__(16) float As[64 * 68];

    const int t = threadIdx.x;
    const int m0 = blockIdx.x * 64;

    if (H0) {
        // ---- stage w_in (overlays Ws[0:4096]) + x tile ----
        for (int i = t; i < 64 * 64; i += 256) Ws[i] = Wh0[i];
        for (int rr = 0; rr < 64; rr += 16) {
            int r = rr + (t >> 4);
            int c4 = (t & 15) * 4;
            int row = m0 + r;
            float4 v = make_float4(0.f, 0.f, 0.f, 0.f);
            if (row < M) v = *(const float4*)&A[(size_t)row * 64 + c4];
            *(float4*)&As[r * 68 + c4] = v;
        }
        __syncthreads();

        // ---- h = relu(x @ w_in + b_in), same layout as old gemm_h0 ----
        const int tc = t & 15, tr = t >> 4;
        float4 hacc[4];
        float4 bv = *(const float4*)&bh0[tc * 4];
#pragma unroll
        for (int i = 0; i < 4; ++i) hacc[i] = bv;
#pragma unroll 8
        for (int k = 0; k < 64; ++k) {
            float4 w = *(const float4*)&Ws[k * 64 + tc * 4];
#pragma unroll
            for (int i = 0; i < 4; ++i) {
                float a = As[(tr + i * 16) * 68 + k];
                hacc[i].x = fmaf(a, w.x, hacc[i].x);
                hacc[i].y = fmaf(a, w.y, hacc[i].y);
                hacc[i].z = fmaf(a, w.z, hacc[i].z);
                hacc[i].w = fmaf(a, w.w, hacc[i].w);
            }
        }
        __syncthreads();   // all reads of As/Ws done before overwrite

        // ---- write relu(h) back into As; stage W=[w1a|w1b] over Ws ----
#pragma unroll
        for (int i = 0; i < 4; ++i) {
            float4 o = hacc[i];
            o.x = fmaxf(o.x, 0.f); o.y = fmaxf(o.y, 0.f);
            o.z = fmaxf(o.z, 0.f); o.w = fmaxf(o.w, 0.f);
            *(float4*)&As[(tr + i * 16) * 68 + tc * 4] = o;
        }
        for (int i = t; i < 64 * 128; i += 256) {
            int k = i >> 7, n = i & 127;
            Ws[i] = W[(size_t)((n < 64 ? k : 64 + k)) * 64 + (n & 63)];
        }
        __syncthreads();
    } else {
        for (int i = t; i < 64 * 128; i += 256) {
            int k = i >> 7, n = i & 127;
            Ws[i] = W[(size_t)((n < 64 ? k : 64 + k)) * 64 + (n & 63)];
        }
        {
            int c4 = (t & 15) * 4;
            float sc[4], sh[4];
            if (BN) {
                float invM = 1.f / (float)M;
#pragma unroll
                for (int j = 0; j < 4; ++j) {
                    int c = c4 + j;
                    float mu = stats[c] * invM;
                    float var = fmaxf(stats[64 + c] * invM - mu * mu, 0.f);
                    float s = gamma[c] * rsqrtf(var + BN_EPS);
                    sc[j] = s; sh[j] = beta[c] - mu * s;
                }
            }
            for (int rr = 0; rr < 64; rr += 16) {
                int r = rr + (t >> 4);
                int row = m0 + r;
                float4 v = make_float4(0.f, 0.f, 0.f, 0.f);
                if (row < M) v = *(const float4*)&A[(size_t)row * 64 + c4];
                if (BN) {
                    v.x = fmaxf(fmaf(v.x, sc[0], sh[0]), 0.f);
                    v.y = fmaxf(fmaf(v.y, sc[1], sh[1]), 0.f);
                    v.z = fmaxf(fmaf(v.z, sc[2], sh[2]), 0.f);
                    v.w = fmaxf(fmaf(v.w, sc[3], sh[3]), 0.f);
                }
                *(float4*)&As[r * 68 + c4] = v;
            }
        }
        __syncthreads();
    }

    const int tc = t & 31, tr = t >> 5;
    float4 acc[8];
#pragma unroll
    for (int i = 0; i < 8; ++i) acc[i] = make_float4(0.f, 0.f, 0.f, 0.f);
#pragma unroll 8
    for (int k = 0; k < 64; ++k) {
        float4 w = *(const float4*)&Ws[k * 128 + tc * 4];
#pragma unroll
        for (int i = 0; i < 8; ++i) {
            float a = As[(tr + i * 8) * 68 + k];
            acc[i].x = fmaf(a, w.x, acc[i].x);
            acc[i].y = fmaf(a, w.y, acc[i].y);
            acc[i].z = fmaf(a, w.z, acc[i].z);
            acc[i].w = fmaf(a, w.w, acc[i].w);
        }
    }
#pragma unroll
    for (int i = 0; i < 8; ++i) {
        int row = m0 + tr + i * 8;
        if (row < M) {
            half4 o = { (_Float16)acc[i].x, (_Float16)acc[i].y,
                        (_Float16)acc[i].z, (_Float16)acc[i].w };
            *(half4*)&PQ[(size_t)row * 128 + tc * 4] = o;
        }
    }
}

// ---------------------------------------------------------------------------
// Fused head: out = relu(BN(h) @ w_m1 + b_m1) @ w_m2 + b_m2
// ---------------------------------------------------------------------------
__global__ __launch_bounds__(256) void head_fused(
    const float* __restrict__ hagg, const float* __restrict__ stats,
    const float* __restrict__ gamma, const float* __restrict__ beta,
    const float* __restrict__ w_m1, const float* __restrict__ b_m1,
    const float* __restrict__ w_m2, const float* __restrict__ b_m2,
    float* __restrict__ out, int M)
{
    __shared__ __align__(16) float Ws1[64 * 64];
    __shared__ __align__(16) float Ws2[64 * 32];
    __shared__ __align__(16) float As[64 * 68];
    __shared__ __align__(16) float Ts[64 * 68];

    const int t = threadIdx.x;
    const int m0 = blockIdx.x * 64;

    for (int i = t; i < 64 * 64; i += 256) Ws1[i] = w_m1[i];
    for (int i = t; i < 64 * 32; i += 256) Ws2[i] = w_m2[i];
    {
        int c4 = (t & 15) * 4;
        float sc[4], sh[4];
        float invM = 1.f / (float)M;
#pragma unroll
        for (int j = 0; j < 4; ++j) {
            int c = c4 + j;
            float mu = stats[c] * invM;
            float var = fmaxf(stats[64 + c] * invM - mu * mu, 0.f);
            float s = gamma[c] * rsqrtf(var + BN_EPS);
            sc[j] = s; sh[j] = beta[c] - mu * s;
        }
        for (int rr = 0; rr < 64; rr += 16) {
            int r = rr + (t >> 4);
            int row = m0 + r;
            float4 v = make_float4(0.f, 0.f, 0.f, 0.f);
            if (row < M) v = *(const float4*)&hagg[(size_t)row * 64 + c4];
            v.x = fmaxf(fmaf(v.x, sc[0], sh[0]), 0.f);
            v.y = fmaxf(fmaf(v.y, sc[1], sh[1]), 0.f);
            v.z = fmaxf(fmaf(v.z, sc[2], sh[2]), 0.f);
            v.w = fmaxf(fmaf(v.w, sc[3], sh[3]), 0.f);
            *(float4*)&As[r * 68 + c4] = v;
        }
    }
    __syncthreads();

    {
        const int tc = t & 15, tr = t >> 4;
        float4 acc[4];
        float4 bv = *(const float4*)&b_m1[tc * 4];
#pragma unroll
        for (int i = 0; i < 4; ++i) acc[i] = bv;
#pragma unroll 8
        for (int k = 0; k < 64; ++k) {
            float4 w = *(const float4*)&Ws1[k * 64 + tc * 4];
#pragma unroll
            for (int i = 0; i < 4; ++i) {
                float a = As[(tr + i * 16) * 68 + k];
                acc[i].x = fmaf(a, w.x, acc[i].x);
                acc[i].y = fmaf(a, w.y, acc[i].y);
                acc[i].z = fmaf(a, w.z, acc[i].z);
                acc[i].w = fmaf(a, w.w, acc[i].w);
            }
        }
#pragma unroll
        for (int i = 0; i < 4; ++i) {
            float4 o = acc[i];
            o.x = fmaxf(o.x, 0.f); o.y = fmaxf(o.y, 0.f);
            o.z = fmaxf(o.z, 0.f); o.w = fmaxf(o.w, 0.f);
            *(float4*)&Ts[(tr + i * 16) * 68 + tc * 4] = o;
        }
    }
    __syncthreads();

    {
        const int tc = t & 7, tr = t >> 3;
        float4 acc[2];
        float4 bv = *(const float4*)&b_m2[tc * 4];
        acc[0] = bv; acc[1] = bv;
#pragma unroll 8
        for (int k = 0; k < 64; ++k) {
            float4 w = *(const float4*)&Ws2[k * 32 + tc * 4];
#pragma unroll
            for (int i = 0; i < 2; ++i) {
                float a = Ts[(tr + i * 32) * 68 + k];
                acc[i].x = fmaf(a, w.x, acc[i].x);
                acc[i].y = fmaf(a, w.y, acc[i].y);
                acc[i].z = fmaf(a, w.z, acc[i].z);
                acc[i].w = fmaf(a, w.w, acc[i].w);
            }
        }
#pragma unroll
        for (int i = 0; i < 2; ++i) {
            int row = m0 + tr + i * 32;
            if (row < M) *(float4*)&out[(size_t)row * 32 + tc * 4] = acc[i];
        }
    }
}

// ---------------------------------------------------------------------------
// CSR build: hist(+within +pack fused) -> scan_partial -> scan_add2 ->
// fill3 (atomic-free: pos = starts[tgt] + within)
// ---------------------------------------------------------------------------
__global__ __launch_bounds__(256) void hist_pack(const int* __restrict__ tgt,
    int* __restrict__ cnt, int* __restrict__ within, int E,
    const float* __restrict__ w2, const float* __restrict__ w1,
    _Float16* __restrict__ w2h, _Float16* __restrict__ w1ch,
    float* __restrict__ stats)
{
    const int gE = (E + 255) >> 8;
    const int b = blockIdx.x;
    if (b < gE) {
        int e = b * 256 + threadIdx.x;
        if (e < E) within[e] = atomicAdd(&cnt[tgt[e]], 1);
        return;
    }
    int id = (b - gE) * 256 + threadIdx.x;
    if (id < 256) stats[id] = 0.f;
    if (id < 1024) {
        int l = id >> 9, rem = id & 511;
        int frag = rem >> 6, lane = rem & 63;
        int nt = frag >> 1, kc = frag & 1;
        const float* W = w2 + (size_t)l * 4096;
        _Float16* O = w2h + (size_t)l * 4096 + (frag * 64 + lane) * 8;
        int n = nt * 16 + (lane & 15);
        int k0 = kc * 32 + (lane >> 4) * 8;
#pragma unroll
        for (int j = 0; j < 8; ++j) O[j] = (_Float16)W[(k0 + j) * 64 + n];
    } else if (id < 1536) {
        // w1ch: B[k][n] = w1c[k & 15][n], K=32 (duplicated halves), 4 nt tiles
        int rem2 = id - 1024;
        int l = rem2 >> 8, rem = rem2 & 255;
        int nt = rem >> 6, lane = rem & 63;
        const float* W1C = w1 + (size_t)l * 144 * 64 + 128 * 64;
        _Float16* O = w1ch + (size_t)l * 2048 + (nt * 64 + lane) * 8;
        int n = nt * 16 + (lane & 15);
        int k0 = (lane >> 4) * 8;
#pragma unroll
        for (int j = 0; j < 8; ++j)
            O[j] = (_Float16)W1C[((k0 + j) & 15) * 64 + n];
    }
}

__global__ __launch_bounds__(256) void scan_partial(const int* __restrict__ cnt,
                                                    int* __restrict__ part, int M)
{
    __shared__ int s[256];
    int i = blockIdx.x * 256 + threadIdx.x;
    s[threadIdx.x] = (i < M) ? cnt[i] : 0;
    __syncthreads();
    for (int off = 128; off > 0; off >>= 1) {
        if (threadIdx.x < off) s[threadIdx.x] += s[threadIdx.x + off];
        __syncthreads();
    }
    if (threadIdx.x == 0) part[blockIdx.x] = s[0];
}

// scan_add2: block computes its own prefix offset (sum part[0..bid)), then
// in-block exclusive scan of cnt.  Output = exclusive starts (unmutated).
__global__ __launch_bounds__(256) void scan_add2(int* __restrict__ cnt,
    const int* __restrict__ part, int M, int nb)
{
    __shared__ int s[256];
    const int t = threadIdx.x;
    const int bid = blockIdx.x;

    int v0 = (t < bid && t < nb) ? part[t] : 0;
    s[t] = v0;
    __syncthreads();
    for (int off = 128; off > 0; off >>= 1) {
        if (t < off) s[t] += s[t + off];
        __syncthreads();
    }
    const int base = s[0];
    __syncthreads();

    int i = bid * 256 + t;
    int v = (i < M) ? cnt[i] : 0;
    s[t] = v;
    __syncthreads();
    for (int off = 1; off < 256; off <<= 1) {
        int a = (t >= off) ? s[t - off] : 0;
        __syncthreads();
        s[t] += a;
        __syncthreads();
    }
    if (i < M) cnt[i] = base + s[t] - v;   // exclusive
}

// fill3: atomic-free CSR fill.  pos = starts[tgt] + within[e]; one 8B write.
__global__ __launch_bounds__(256) void fill3(const int* __restrict__ tgt,
    const int* __restrict__ src, const int* __restrict__ starts,
    const int* __restrict__ within, int2* __restrict__ epair, int E)
{
    int e = blockIdx.x * 256 + threadIdx.x;
    if (e < E) {
        int pos = starts[tgt[e]] + within[e];
        epair[pos] = make_int2(src[e], e);   // .x = src node, .y = edge id
    }
}

// ---------------------------------------------------------------------------
// Fused per-node edge-MLP + segmented max + BN stats.
//   R18 structure: barrier-free per-wave micro-tile pipeline (16 edges/group,
//   private LDS slice per wave, no __syncthreads in main loop).  ea@w1c via
//   MFMA (exact hi/lo split), C'+D fused, lnod via binary search + shfl.
//   R21: reads starts[] (exclusive, E sentinel) + int2 epair (one 8B load).
// ---------------------------------------------------------------------------
#define NPB 16
#define WED 16     // edges per wave micro-tile
#define TSH 72     // t1/q stride in halfs (144 B -> 2-way b128, free)
#define EST 40     // eash stride in halfs (80 B, 16B-aligned rows, 2-way)
#define QSL (WED * TSH)   // 1152 halfs per wave slice
#define ESL (WED * EST)   //  640 halfs per wave slice

__global__ __launch_bounds__(256, 4) void node_agg(
    const _Float16* __restrict__ pq, const float* __restrict__ ea,
    const int* __restrict__ starts, const int2* __restrict__ epair,
    const _Float16* __restrict__ w1cbG, const float* __restrict__ b1,
    const _Float16* __restrict__ w2h, const float* __restrict__ b2,
    float* __restrict__ hout, float* __restrict__ stats, int M, int E)
{
    __shared__ __align__(16) _Float16 t1h[4 * QSL];    // 9.0 KB
    __shared__ __align__(16) _Float16 eash[4 * ESL];   // 5.0 KB
    __shared__ __align__(16) float ps[NPB * 68];       // 4.25 KB
    __shared__ __align__(16) unsigned rmu[NPB * 68];   // 4.25 KB
    __shared__ int endsL[NPB + 1];
    // total ~22.6 KB -> 6 blocks/CU (LDS-limited)

    const int t = threadIdx.x;
    const int lane = t & 63;
    const int wid = t >> 6;
    const int n0 = blockIdx.x * NPB;
    const int c = lane;
    const int quad = lane >> 4;
    const int col = lane & 15;
    const int ej = lane >> 2;    // local edge 0..15 (4 lanes per edge)
    const int j4 = lane & 3;

    if (t <= NPB) {
        int n = n0 + t;
        endsL[t] = (n < M) ? starts[n] : E;   // start of node n (E sentinel)
    }
    for (int nn = wid; nn < NPB; nn += 4) {
        int node = n0 + nn;
        ps[nn * 68 + c] =
            ((node < M) ? (float)pq[(size_t)node * 128 + c] : 0.f) + b1[c];
    }
    for (int i = t; i < NPB * 68; i += 256) rmu[i] = 0u;   // 0 < enc(anything)

    half8 bfrag[4][2];
#pragma unroll
    for (int nt = 0; nt < 4; ++nt)
#pragma unroll
        for (int kc = 0; kc < 2; ++kc)
            bfrag[nt][kc] = *(const half8*)(w2h + ((nt * 2 + kc) * 64 + lane) * 8);
    half8 w1cb[4];
#pragma unroll
    for (int nt = 0; nt < 4; ++nt)
        w1cb[nt] = *(const half8*)(w1cbG + (nt * 64 + lane) * 8);

    __syncthreads();

    const int eBeg = endsL[0], eEnd = endsL[NPB];
    const int emax = (eEnd > 0) ? eEnd - 1 : 0;
    const int STEP = 4 * WED;                 // 64
    const int g0 = eBeg + wid * WED;          // this wave's first group

    _Float16* tsl = t1h + wid * QSL;          // private slices
    _Float16* esl = eash + wid * ESL;

    // per-wave prefetch state (16 VGPR): payload(g), indices(g+1)
    half8  qv0 = {}, qv1 = {};
    float4 eav = make_float4(0.f, 0.f, 0.f, 0.f);
    int sidN = 0, peN = 0;

    if (g0 < eEnd) {
        int2 ep0 = epair[min(g0 + ej, emax)];
        const _Float16* qs = pq + (size_t)ep0.x * 128 + 64 + j4 * 16;
        qv0 = *(const half8*)(qs);
        qv1 = *(const half8*)(qs + 8);
        eav = *(const float4*)&ea[(size_t)ep0.y * 16 + j4 * 4];
        int2 ep1 = epair[min(g0 + STEP + ej, emax)];
        sidN = ep1.x;
        peN  = ep1.y;
    }

    for (int gs = g0; gs < eEnd; gs += STEP) {
        // ---- 1. write payload(gs) into own slice (same-wave DS order) ----
        {
            _Float16* qd = tsl + ej * TSH + j4 * 16;
            *(half8*)qd = qv0;
            *(half8*)(qd + 8) = qv1;

            float xs[4] = { eav.x, eav.y, eav.z, eav.w };
            half4 hi4, lo4;
#pragma unroll
            for (int j = 0; j < 4; ++j) {
                _Float16 hj = (_Float16)xs[j];
                hi4[j] = hj;
                lo4[j] = (_Float16)(xs[j] - (float)hj);
            }
            _Float16* ed = esl + ej * EST + j4 * 4;
            *(half4*)ed = hi4;          // hi block: halfs [0,16)
            *(half4*)(ed + 16) = lo4;   // lo block: halfs [16,32)
        }

        // ---- 2. issue payload(gs+STEP); 3. issue idx(gs+2*STEP) ----
        if (gs + STEP < eEnd) {
            const _Float16* qs = pq + (size_t)sidN * 128 + 64 + j4 * 16;
            qv0 = *(const half8*)(qs);
            qv1 = *(const half8*)(qs + 8);
            eav = *(const float4*)&ea[(size_t)peN * 16 + j4 * 4];
            if (gs + 2 * STEP < eEnd) {
                int2 ep2 = epair[min(gs + 2 * STEP + ej, emax)];
                sidN = ep2.x;
                peN  = ep2.y;
            }
        }
        __builtin_amdgcn_sched_barrier(0);   // pin load issue before compute

        // ---- 4. lnod: lane computes its local edge's node, then shfl ----
        int Lv = 0;
        {
            int gp = gs + (lane & 15);
            int lo = 0, hi = NPB;
#pragma unroll
            for (int s = 0; s < 4; ++s) {
                int mid = (lo + hi) >> 1;
                bool geq = gp >= endsL[mid];
                lo = geq ? mid : lo;
                hi = geq ? hi : mid;
            }
            Lv = lo;
        }
        const int L0 = __shfl(Lv, quad * 4 + 0, 64);
        const int L1 = __shfl(Lv, quad * 4 + 1, 64);
        const int L2 = __shfl(Lv, quad * 4 + 2, 64);
        const int L3 = __shfl(Lv, quad * 4 + 3, 64);

        // ---- 5. C' : C-in = ps + q, += ea@w1c (MFMA), relu -> t1 ----
        _Float16* qb = tsl + (quad * 4) * TSH + col;
        const float* p0 = &ps[L0 * 68 + col];
        const float* p1 = &ps[L1 * 68 + col];
        const float* p2 = &ps[L2 * 68 + col];
        const float* p3 = &ps[L3 * 68 + col];
        floatx4 acc[4];
#pragma unroll
        for (int nt = 0; nt < 4; ++nt) {
            acc[nt][0] = (float)qb[0 * TSH + nt * 16] + p0[nt * 16];
            acc[nt][1] = (float)qb[1 * TSH + nt * 16] + p1[nt * 16];
            acc[nt][2] = (float)qb[2 * TSH + nt * 16] + p2[nt * 16];
            acc[nt][3] = (float)qb[3 * TSH + nt * 16] + p3[nt * 16];
        }
        half8 af = *(const half8*)&esl[col * EST + quad * 8];
#pragma unroll
        for (int nt = 0; nt < 4; ++nt)
            acc[nt] = __builtin_amdgcn_mfma_f32_16x16x32_f16(
                af, w1cb[nt], acc[nt], 0, 0, 0);
#pragma unroll
        for (int nt = 0; nt < 4; ++nt) {
#pragma unroll
            for (int r = 0; r < 4; ++r)
                qb[r * TSH + nt * 16] = (_Float16)fmaxf(acc[nt][r], 0.f);
        }

        // ---- 6. D : m = t1 @ w2 (MFMA), segmented max into rmu ----
        floatx4 accD[4] = {{0.f,0.f,0.f,0.f},{0.f,0.f,0.f,0.f},
                           {0.f,0.f,0.f,0.f},{0.f,0.f,0.f,0.f}};
#pragma unroll
        for (int kc = 0; kc < 2; ++kc) {
            half8 a = *(const half8*)&tsl[col * TSH + kc * 32 + quad * 8];
#pragma unroll
            for (int nt = 0; nt < 4; ++nt)
                accD[nt] = __builtin_amdgcn_mfma_f32_16x16x32_f16(
                    a, bfrag[nt][kc], accD[nt], 0, 0, 0);
        }
        const int gbase = gs + quad * 4;
#pragma unroll
        for (int nt = 0; nt < 4; ++nt) {
            int curL = -1;
            float best = 0.f;
#pragma unroll
            for (int r = 0; r < 4; ++r) {
                int ge = gbase + r;
                if (ge < eEnd) {
                    int L = (r == 0) ? L0 : (r == 1) ? L1
                          : (r == 2) ? L2 : L3;
                    float v = accD[nt][r];
                    if (L != curL) {
                        if (curL >= 0)
                            atomicMax(&rmu[curL * 68 + nt * 16 + col],
                                      enc(best));
                        curL = L; best = v;
                    } else best = fmaxf(best, v);
                }
            }
            if (curL >= 0)
                atomicMax(&rmu[curL * 68 + nt * 16 + col], enc(best));
        }
    }

    __syncthreads();   // all waves' rmu atomics done

    // ---- final store (+b2, raw agg; BN deferred to consumer) + BN stats ----
    for (int idx = t; idx < NPB * 64; idx += 256) {
        int L = idx >> 6, cc = idx & 63;
        int node = n0 + L;
        float v = 0.f;
        if (node < M) {
            if (endsL[L + 1] > endsL[L]) v = dec(rmu[L * 68 + cc]) + b2[cc];
            hout[(size_t)node * 64 + cc] = v;
        }
        ((float*)rmu)[L * 68 + cc] = v;   // own slot: no race
    }
    __syncthreads();
    if (t < 64) {
        float s = 0.f, s2 = 0.f;
#pragma unroll
        for (int L = 0; L < NPB; ++L) {
            float v = ((float*)rmu)[L * 68 + t];
            s += v;
            s2 = fmaf(v, v, s2);
        }
        atomicAdd(&stats[t], s);
        atomicAdd(&stats[64 + t], s2);
    }
}

// ---------------------------------------------------------------------------
extern "C" void kernel_launch(void* const* d_in, const int* in_sizes, int n_in,
                              void* d_out, int out_size, void* d_ws, size_t ws_size,
                              hipStream_t stream)
{
    const float* x     = (const float*)d_in[0];
    const int*   eidx  = (const int*)  d_in[1];
    const float* ea    = (const float*)d_in[2];
    const float* w_in  = (const float*)d_in[3];
    const float* b_in  = (const float*)d_in[4];
    const float* w1    = (const float*)d_in[5];
    const float* b1    = (const float*)d_in[6];
    const float* w2    = (const float*)d_in[7];
    const float* b2    = (const float*)d_in[8];
    const float* gamma = (const float*)d_in[9];
    const float* beta  = (const float*)d_in[10];
    const float* w_m1  = (const float*)d_in[11];
    const float* b_m1  = (const float*)d_in[12];
    const float* w_m2  = (const float*)d_in[13];
    const float* b_m2  = (const float*)d_in[14];

    const int M = in_sizes[0] / 64;   // n_nodes
    const int E = in_sizes[1] / 2;    // n_edges
    const int* src = eidx;            // edge_index[0]
    const int* tgt = eidx + E;        // edge_index[1] (aggregation target)

    // ws: hagg | pqh | starts | epair | within | part | stats = 35.6 MB
    float* hagg   = (float*)d_ws;
    _Float16* pqh = (_Float16*)(hagg + (size_t)M * 64);
    int* starts   = (int*)(pqh + (size_t)M * 128);
    int2* epair   = (int2*)(starts + M);
    int* within   = (int*)(epair + E);
    const int nb  = (M + 255) / 256;
    int* part     = within + E;
    float* stats  = (float*)(part + nb);
    // d_out scratch: w2h | w1ch — dead before head writes d_out
    _Float16* w2h  = (_Float16*)d_out;
    _Float16* w1ch = (_Float16*)((char*)d_out + 16384);

    dim3 blk(256);
    const int gm64 = (M + 63) / 64;
    const int gE   = (E + 255) / 256;

    // CSR build (atomic-free fill) + weight pack (+stats zero)
    (void)hipMemsetAsync(starts, 0, (size_t)M * 4, stream);
    hist_pack<<<gE + 6, blk, 0, stream>>>(tgt, starts, within, E,
                                          w2, w1, w2h, w1ch, stats);
    scan_partial<<<nb, blk, 0, stream>>>(starts, part, M);
    scan_add2<<<nb, blk, 0, stream>>>(starts, part, M, nb);
    fill3<<<gE, blk, 0, stream>>>(tgt, src, starts, within, epair, E);

    for (int l = 0; l < 2; ++l) {
        const float* w1l = w1 + (size_t)l * 144 * 64;
        if (l == 0)
            gemm_pq<true, false><<<gm64, blk, 0, stream>>>(x, w1l, w_in, b_in,
                pqh, nullptr, nullptr, nullptr, M);
        else
            gemm_pq<false, true><<<gm64, blk, 0, stream>>>(hagg, w1l,
                nullptr, nullptr, pqh, stats, gamma, beta, M);
        node_agg<<<(M + NPB - 1) / NPB, blk, 0, stream>>>(pqh, ea,
            starts, epair,
            w1ch + (size_t)l * 2048, b1 + l * 64,
            w2h + (size_t)l * 4096, b2 + l * 64,
            hagg, stats + l * 128, M, E);
    }

    // out = relu(BN1(h) @ w_m1 + b_m1) @ w_m2 + b_m2
    head_fused<<<gm64, blk, 0, stream>>>(hagg, stats + 128, gamma + 64, beta + 64,
        w_m1, b_m1, w_m2, b_m2, (float*)d_out, M);
}

// Round 12
// 469.253 us; speedup vs baseline: 1.1384x; 1.0225x over previous
//
#include <hip/hip_runtime.h>
#include <float.h>

// ---------------------------------------------------------------------------
// MPNN forward.  msg@w1 decomposed: per-node p=h@w1a, q=h@w1b (fused gemm_pq,
// f16 out, BN fused on A-load), per-edge ea@w1c; edge GEMM t1@w2 f16 MFMA.
// R22: fill3 co-launched inside gemm<H0> (role-split grid; fill = scattered
// fire-and-forget stores -> tolerates the 49KB-LDS 3-blocks/CU residency;
// hist NOT fused because its atomicAdd RETURN makes it latency-bound).
// Stream order still guarantees fill runs after scan_add2.
// R21: atomic-free CSR fill (within = hist's atomicAdd return; pos =
// starts[tgt]+within; one int2 {src,e} write); node_agg reads starts[] +
// 8B epair broadcast.
// node_agg: R18 barrier-free per-wave pipeline kept (pinned ~123us over 6
// rewrites; no pipe >23% busy -> line-granular gather wall).
// R19/R20: gemm_h0 fused into gemm_pq<H0>; scan_part2 folded into scan_add2;
// pack fused into hist_pack.
//
// ws: hagg 12.8M | pqh 12.8M | starts 200K | epair 6.4M | within 3.2M |
//   part | stats(256f) = 35.6 MB  (proven bound 38.6 MB).
// d_out scratch: w2h 16K | w1ch 8K (dead before head writes d_out).
// ---------------------------------------------------------------------------

typedef _Float16 half8 __attribute__((ext_vector_type(8)));
typedef _Float16 half4 __attribute__((ext_vector_type(4)));
typedef float floatx4 __attribute__((ext_vector_type(4)));

#define BN_EPS 1e-5f

__device__ __forceinline__ unsigned enc(float f) {
    unsigned u = __float_as_uint(f);
    return (u & 0x80000000u) ? ~u : (u | 0x80000000u);
}
__device__ __forceinline__ float dec(unsigned u) {
    return (u & 0x80000000u) ? __uint_as_float(u & 0x7fffffffu)
                             : __uint_as_float(~u);
}

// ---------------------------------------------------------------------------
// Fused: blocks [0,gm64) = h0+pq GEMM (h=relu(x@w_in+b_in) in-LDS, then
// p|q = h@[w1a|w1b], f16 out); blocks [gm64, gm64+gE) = atomic-free CSR
// fill (pos = starts[tgt]+within, one int2 write).
// ---------------------------------------------------------------------------
__global__ __launch_bounds__(256) void h0pq_fill(
    const float* __restrict__ A, const float* __restrict__ W,
    const float* __restrict__ Wh0, const float* __restrict__ bh0,
    _Float16* __restrict__ PQ, int M, int gm64,
    const int* __restrict__ tgt, const int* __restrict__ src,
    const int* __restrict__ starts, const int* __restrict__ within,
    int2* __restrict__ epair, int E)
{
    __shared__ __align__(16) float Ws[64 * 128];
    __shared__ __align__(16) float As[64 * 68];

    const int t = threadIdx.x;

    if (blockIdx.x >= gm64) {
        // ---- fill role: atomic-free CSR fill, one 8B scattered store ----
        int e = (blockIdx.x - gm64) * 256 + t;
        if (e < E) {
            int pos = starts[tgt[e]] + within[e];
            epair[pos] = make_int2(src[e], e);   // .x = src node, .y = edge
        }
        return;
    }

    const int m0 = blockIdx.x * 64;

    // ---- stage w_in (overlays Ws[0:4096]) + x tile ----
    for (int i = t; i < 64 * 64; i += 256) Ws[i] = Wh0[i];
    for (int rr = 0; rr < 64; rr += 16) {
        int r = rr + (t >> 4);
        int c4 = (t & 15) * 4;
        int row = m0 + r;
        float4 v = make_float4(0.f, 0.f, 0.f, 0.f);
        if (row < M) v = *(const float4*)&A[(size_t)row * 64 + c4];
        *(float4*)&As[r * 68 + c4] = v;
    }
    __syncthreads();

    // ---- h = relu(x @ w_in + b_in), same layout as old gemm_h0 ----
    {
        const int tc = t & 15, tr = t >> 4;
        float4 hacc[4];
        float4 bv = *(const float4*)&bh0[tc * 4];
#pragma unroll
        for (int i = 0; i < 4; ++i) hacc[i] = bv;
#pragma unroll 8
        for (int k = 0; k < 64; ++k) {
            float4 w = *(const float4*)&Ws[k * 64 + tc * 4];
#pragma unroll
            for (int i = 0; i < 4; ++i) {
                float a = As[(tr + i * 16) * 68 + k];
                hacc[i].x = fmaf(a, w.x, hacc[i].x);
                hacc[i].y = fmaf(a, w.y, hacc[i].y);
                hacc[i].z = fmaf(a, w.z, hacc[i].z);
                hacc[i].w = fmaf(a, w.w, hacc[i].w);
            }
        }
        __syncthreads();   // all reads of As/Ws done before overwrite

        // ---- write relu(h) into As; stage W=[w1a|w1b] over Ws ----
#pragma unroll
        for (int i = 0; i < 4; ++i) {
            float4 o = hacc[i];
            o.x = fmaxf(o.x, 0.f); o.y = fmaxf(o.y, 0.f);
            o.z = fmaxf(o.z, 0.f); o.w = fmaxf(o.w, 0.f);
            *(float4*)&As[(tr + i * 16) * 68 + tc * 4] = o;
        }
    }
    for (int i = t; i < 64 * 128; i += 256) {
        int k = i >> 7, n = i & 127;
        Ws[i] = W[(size_t)((n < 64 ? k : 64 + k)) * 64 + (n & 63)];
    }
    __syncthreads();

    const int tc = t & 31, tr = t >> 5;
    float4 acc[8];
#pragma unroll
    for (int i = 0; i < 8; ++i) acc[i] = make_float4(0.f, 0.f, 0.f, 0.f);
#pragma unroll 8
    for (int k = 0; k < 64; ++k) {
        float4 w = *(const float4*)&Ws[k * 128 + tc * 4];
#pragma unroll
        for (int i = 0; i < 8; ++i) {
            float a = As[(tr + i * 8) * 68 + k];
            acc[i].x = fmaf(a, w.x, acc[i].x);
            acc[i].y = fmaf(a, w.y, acc[i].y);
            acc[i].z = fmaf(a, w.z, acc[i].z);
            acc[i].w = fmaf(a, w.w, acc[i].w);
        }
    }
#pragma unroll
    for (int i = 0; i < 8; ++i) {
        int row = m0 + tr + i * 8;
        if (row < M) {
            half4 o = { (_Float16)acc[i].x, (_Float16)acc[i].y,
                        (_Float16)acc[i].z, (_Float16)acc[i].w };
            *(half4*)&PQ[(size_t)row * 128 + tc * 4] = o;
        }
    }
}

// ---------------------------------------------------------------------------
// p|q GEMM with BN+relu fused on A-load (layer 1).
// ---------------------------------------------------------------------------
__global__ __launch_bounds__(256) void gemm_pq_bn(
    const float* __restrict__ A, const float* __restrict__ W,
    _Float16* __restrict__ PQ, const float* __restrict__ stats,
    const float* __restrict__ gamma, const float* __restrict__ beta, int M)
{
    __shared__ __align__(16) float Ws[64 * 128];
    __shared__ __align__(16) float As[64 * 68];

    const int t = threadIdx.x;
    const int m0 = blockIdx.x * 64;

    for (int i = t; i < 64 * 128; i += 256) {
        int k = i >> 7, n = i & 127;
        Ws[i] = W[(size_t)((n < 64 ? k : 64 + k)) * 64 + (n & 63)];
    }
    {
        int c4 = (t & 15) * 4;
        float sc[4], sh[4];
        float invM = 1.f / (float)M;
#pragma unroll
        for (int j = 0; j < 4; ++j) {
            int c = c4 + j;
            float mu = stats[c] * invM;
            float var = fmaxf(stats[64 + c] * invM - mu * mu, 0.f);
            float s = gamma[c] * rsqrtf(var + BN_EPS);
            sc[j] = s; sh[j] = beta[c] - mu * s;
        }
        for (int rr = 0; rr < 64; rr += 16) {
            int r = rr + (t >> 4);
            int row = m0 + r;
            float4 v = make_float4(0.f, 0.f, 0.f, 0.f);
            if (row < M) v = *(const float4*)&A[(size_t)row * 64 + c4];
            v.x = fmaxf(fmaf(v.x, sc[0], sh[0]), 0.f);
            v.y = fmaxf(fmaf(v.y, sc[1], sh[1]), 0.f);
            v.z = fmaxf(fmaf(v.z, sc[2], sh[2]), 0.f);
            v.w = fmaxf(fmaf(v.w, sc[3], sh[3]), 0.f);
            *(float4*)&As[r * 68 + c4] = v;
        }
    }
    __syncthreads();

    const int tc = t & 31, tr = t >> 5;
    float4 acc[8];
#pragma unroll
    for (int i = 0; i < 8; ++i) acc[i] = make_float4(0.f, 0.f, 0.f, 0.f);
#pragma unroll 8
    for (int k = 0; k < 64; ++k) {
        float4 w = *(const float4*)&Ws[k * 128 + tc * 4];
#pragma unroll
        for (int i = 0; i < 8; ++i) {
            float a = As[(tr + i * 8) * 68 + k];
            acc[i].x = fmaf(a, w.x, acc[i].x);
            acc[i].y = fmaf(a, w.y, acc[i].y);
            acc[i].z = fmaf(a, w.z, acc[i].z);
            acc[i].w = fmaf(a, w.w, acc[i].w);
        }
    }
#pragma unroll
    for (int i = 0; i < 8; ++i) {
        int row = m0 + tr + i * 8;
        if (row < M) {
            half4 o = { (_Float16)acc[i].x, (_Float16)acc[i].y,
                        (_Float16)acc[i].z, (_Float16)acc[i].w };
            *(half4*)&PQ[(size_t)row * 128 + tc * 4] = o;
        }
    }
}

// ---------------------------------------------------------------------------
// Fused head: out = relu(BN(h) @ w_m1 + b_m1) @ w_m2 + b_m2
// ---------------------------------------------------------------------------
__global__ __launch_bounds__(256) void head_fused(
    const float* __restrict__ hagg, const float* __restrict__ stats,
    const float* __restrict__ gamma, const float* __restrict__ beta,
    const float* __restrict__ w_m1, const float* __restrict__ b_m1,
    const float* __restrict__ w_m2, const float* __restrict__ b_m2,
    float* __restrict__ out, int M)
{
    __shared__ __align__(16) float Ws1[64 * 64];
    __shared__ __align__(16) float Ws2[64 * 32];
    __shared__ __align__(16) float As[64 * 68];
    __shared__ __align__(16) float Ts[64 * 68];

    const int t = threadIdx.x;
    const int m0 = blockIdx.x * 64;

    for (int i = t; i < 64 * 64; i += 256) Ws1[i] = w_m1[i];
    for (int i = t; i < 64 * 32; i += 256) Ws2[i] = w_m2[i];
    {
        int c4 = (t & 15) * 4;
        float sc[4], sh[4];
        float invM = 1.f / (float)M;
#pragma unroll
        for (int j = 0; j < 4; ++j) {
            int c = c4 + j;
            float mu = stats[c] * invM;
            float var = fmaxf(stats[64 + c] * invM - mu * mu, 0.f);
            float s = gamma[c] * rsqrtf(var + BN_EPS);
            sc[j] = s; sh[j] = beta[c] - mu * s;
        }
        for (int rr = 0; rr < 64; rr += 16) {
            int r = rr + (t >> 4);
            int row = m0 + r;
            float4 v = make_float4(0.f, 0.f, 0.f, 0.f);
            if (row < M) v = *(const float4*)&hagg[(size_t)row * 64 + c4];
            v.x = fmaxf(fmaf(v.x, sc[0], sh[0]), 0.f);
            v.y = fmaxf(fmaf(v.y, sc[1], sh[1]), 0.f);
            v.z = fmaxf(fmaf(v.z, sc[2], sh[2]), 0.f);
            v.w = fmaxf(fmaf(v.w, sc[3], sh[3]), 0.f);
            *(float4*)&As[r * 68 + c4] = v;
        }
    }
    __syncthreads();

    {
        const int tc = t & 15, tr = t >> 4;
        float4 acc[4];
        float4 bv = *(const float4*)&b_m1[tc * 4];
#pragma unroll
        for (int i = 0; i < 4; ++i) acc[i] = bv;
#pragma unroll 8
        for (int k = 0; k < 64; ++k) {
            float4 w = *(const float4*)&Ws1[k * 64 + tc * 4];
#pragma unroll
            for (int i = 0; i < 4; ++i) {
                float a = As[(tr + i * 16) * 68 + k];
                acc[i].x = fmaf(a, w.x, acc[i].x);
                acc[i].y = fmaf(a, w.y, acc[i].y);
                acc[i].z = fmaf(a, w.z, acc[i].z);
                acc[i].w = fmaf(a, w.w, acc[i].w);
            }
        }
#pragma unroll
        for (int i = 0; i < 4; ++i) {
            float4 o = acc[i];
            o.x = fmaxf(o.x, 0.f); o.y = fmaxf(o.y, 0.f);
            o.z = fmaxf(o.z, 0.f); o.w = fmaxf(o.w, 0.f);
            *(float4*)&Ts[(tr + i * 16) * 68 + tc * 4] = o;
        }
    }
    __syncthreads();

    {
        const int tc = t & 7, tr = t >> 3;
        float4 acc[2];
        float4 bv = *(const float4*)&b_m2[tc * 4];
        acc[0] = bv; acc[1] = bv;
#pragma unroll 8
        for (int k = 0; k < 64; ++k) {
            float4 w = *(const float4*)&Ws2[k * 32 + tc * 4];
#pragma unroll
            for (int i = 0; i < 2; ++i) {
                float a = Ts[(tr + i * 32) * 68 + k];
                acc[i].x = fmaf(a, w.x, acc[i].x);
                acc[i].y = fmaf(a, w.y, acc[i].y);
                acc[i].z = fmaf(a, w.z, acc[i].z);
                acc[i].w = fmaf(a, w.w, acc[i].w);
            }
        }
#pragma unroll
        for (int i = 0; i < 2; ++i) {
            int row = m0 + tr + i * 32;
            if (row < M) *(float4*)&out[(size_t)row * 32 + tc * 4] = acc[i];
        }
    }
}

// ---------------------------------------------------------------------------
// CSR build: hist(+within +pack fused) -> scan_partial -> scan_add2
// (fill lives in h0pq_fill)
// ---------------------------------------------------------------------------
__global__ __launch_bounds__(256) void hist_pack(const int* __restrict__ tgt,
    int* __restrict__ cnt, int* __restrict__ within, int E,
    const float* __restrict__ w2, const float* __restrict__ w1,
    _Float16* __restrict__ w2h, _Float16* __restrict__ w1ch,
    float* __restrict__ stats)
{
    const int gE = (E + 255) >> 8;
    const int b = blockIdx.x;
    if (b < gE) {
        int e = b * 256 + threadIdx.x;
        if (e < E) within[e] = atomicAdd(&cnt[tgt[e]], 1);
        return;
    }
    int id = (b - gE) * 256 + threadIdx.x;
    if (id < 256) stats[id] = 0.f;
    if (id < 1024) {
        int l = id >> 9, rem = id & 511;
        int frag = rem >> 6, lane = rem & 63;
        int nt = frag >> 1, kc = frag & 1;
        const float* W = w2 + (size_t)l * 4096;
        _Float16* O = w2h + (size_t)l * 4096 + (frag * 64 + lane) * 8;
        int n = nt * 16 + (lane & 15);
        int k0 = kc * 32 + (lane >> 4) * 8;
#pragma unroll
        for (int j = 0; j < 8; ++j) O[j] = (_Float16)W[(k0 + j) * 64 + n];
    } else if (id < 1536) {
        // w1ch: B[k][n] = w1c[k & 15][n], K=32 (duplicated halves), 4 nt tiles
        int rem2 = id - 1024;
        int l = rem2 >> 8, rem = rem2 & 255;
        int nt = rem >> 6, lane = rem & 63;
        const float* W1C = w1 + (size_t)l * 144 * 64 + 128 * 64;
        _Float16* O = w1ch + (size_t)l * 2048 + (nt * 64 + lane) * 8;
        int n = nt * 16 + (lane & 15);
        int k0 = (lane >> 4) * 8;
#pragma unroll
        for (int j = 0; j < 8; ++j)
            O[j] = (_Float16)W1C[((k0 + j) & 15) * 64 + n];
    }
}

__global__ __launch_bounds__(256) void scan_partial(const int* __restrict__ cnt,
                                                    int* __restrict__ part, int M)
{
    __shared__ int s[256];
    int i = blockIdx.x * 256 + threadIdx.x;
    s[threadIdx.x] = (i < M) ? cnt[i] : 0;
    __syncthreads();
    for (int off = 128; off > 0; off >>= 1) {
        if (threadIdx.x < off) s[threadIdx.x] += s[threadIdx.x + off];
        __syncthreads();
    }
    if (threadIdx.x == 0) part[blockIdx.x] = s[0];
}

// scan_add2: block computes its own prefix offset (sum part[0..bid)), then
// in-block exclusive scan of cnt.  Output = exclusive starts (unmutated).
__global__ __launch_bounds__(256) void scan_add2(int* __restrict__ cnt,
    const int* __restrict__ part, int M, int nb)
{
    __shared__ int s[256];
    const int t = threadIdx.x;
    const int bid = blockIdx.x;

    int v0 = (t < bid && t < nb) ? part[t] : 0;
    s[t] = v0;
    __syncthreads();
    for (int off = 128; off > 0; off >>= 1) {
        if (t < off) s[t] += s[t + off];
        __syncthreads();
    }
    const int base = s[0];
    __syncthreads();

    int i = bid * 256 + t;
    int v = (i < M) ? cnt[i] : 0;
    s[t] = v;
    __syncthreads();
    for (int off = 1; off < 256; off <<= 1) {
        int a = (t >= off) ? s[t - off] : 0;
        __syncthreads();
        s[t] += a;
        __syncthreads();
    }
    if (i < M) cnt[i] = base + s[t] - v;   // exclusive
}

// ---------------------------------------------------------------------------
// Fused per-node edge-MLP + segmented max + BN stats.
//   R18 structure: barrier-free per-wave micro-tile pipeline (16 edges/group,
//   private LDS slice per wave, no __syncthreads in main loop).  ea@w1c via
//   MFMA (exact hi/lo split), C'+D fused, lnod via binary search + shfl.
//   R21: reads starts[] (exclusive, E sentinel) + int2 epair (one 8B load).
// ---------------------------------------------------------------------------
#define NPB 16
#define WED 16     // edges per wave micro-tile
#define TSH 72     // t1/q stride in halfs (144 B -> 2-way b128, free)
#define EST 40     // eash stride in halfs (80 B, 16B-aligned rows, 2-way)
#define QSL (WED * TSH)   // 1152 halfs per wave slice
#define ESL (WED * EST)   //  640 halfs per wave slice

__global__ __launch_bounds__(256, 4) void node_agg(
    const _Float16* __restrict__ pq, const float* __restrict__ ea,
    const int* __restrict__ starts, const int2* __restrict__ epair,
    const _Float16* __restrict__ w1cbG, const float* __restrict__ b1,
    const _Float16* __restrict__ w2h, const float* __restrict__ b2,
    float* __restrict__ hout, float* __restrict__ stats, int M, int E)
{
    __shared__ __align__(16) _Float16 t1h[4 * QSL];    // 9.0 KB
    __shared__ __align__(16) _Float16 eash[4 * ESL];   // 5.0 KB
    __shared__ __align__(16) float ps[NPB * 68];       // 4.25 KB
    __shared__ __align__(16) unsigned rmu[NPB * 68];   // 4.25 KB
    __shared__ int endsL[NPB + 1];
    // total ~22.6 KB -> 6 blocks/CU (LDS-limited)

    const int t = threadIdx.x;
    const int lane = t & 63;
    const int wid = t >> 6;
    const int n0 = blockIdx.x * NPB;
    const int c = lane;
    const int quad = lane >> 4;
    const int col = lane & 15;
    const int ej = lane >> 2;    // local edge 0..15 (4 lanes per edge)
    const int j4 = lane & 3;

    if (t <= NPB) {
        int n = n0 + t;
        endsL[t] = (n < M) ? starts[n] : E;   // start of node n (E sentinel)
    }
    for (int nn = wid; nn < NPB; nn += 4) {
        int node = n0 + nn;
        ps[nn * 68 + c] =
            ((node < M) ? (float)pq[(size_t)node * 128 + c] : 0.f) + b1[c];
    }
    for (int i = t; i < NPB * 68; i += 256) rmu[i] = 0u;   // 0 < enc(anything)

    half8 bfrag[4][2];
#pragma unroll
    for (int nt = 0; nt < 4; ++nt)
#pragma unroll
        for (int kc = 0; kc < 2; ++kc)
            bfrag[nt][kc] = *(const half8*)(w2h + ((nt * 2 + kc) * 64 + lane) * 8);
    half8 w1cb[4];
#pragma unroll
    for (int nt = 0; nt < 4; ++nt)
        w1cb[nt] = *(const half8*)(w1cbG + (nt * 64 + lane) * 8);

    __syncthreads();

    const int eBeg = endsL[0], eEnd = endsL[NPB];
    const int emax = (eEnd > 0) ? eEnd - 1 : 0;
    const int STEP = 4 * WED;                 // 64
    const int g0 = eBeg + wid * WED;          // this wave's first group

    _Float16* tsl = t1h + wid * QSL;          // private slices
    _Float16* esl = eash + wid * ESL;

    // per-wave prefetch state (16 VGPR): payload(g), indices(g+1)
    half8  qv0 = {}, qv1 = {};
    float4 eav = make_float4(0.f, 0.f, 0.f, 0.f);
    int sidN = 0, peN = 0;

    if (g0 < eEnd) {
        int2 ep0 = epair[min(g0 + ej, emax)];
        const _Float16* qs = pq + (size_t)ep0.x * 128 + 64 + j4 * 16;
        qv0 = *(const half8*)(qs);
        qv1 = *(const half8*)(qs + 8);
        eav = *(const float4*)&ea[(size_t)ep0.y * 16 + j4 * 4];
        int2 ep1 = epair[min(g0 + STEP + ej, emax)];
        sidN = ep1.x;
        peN  = ep1.y;
    }

    for (int gs = g0; gs < eEnd; gs += STEP) {
        // ---- 1. write payload(gs) into own slice (same-wave DS order) ----
        {
            _Float16* qd = tsl + ej * TSH + j4 * 16;
            *(half8*)qd = qv0;
            *(half8*)(qd + 8) = qv1;

            float xs[4] = { eav.x, eav.y, eav.z, eav.w };
            half4 hi4, lo4;
#pragma unroll
            for (int j = 0; j < 4; ++j) {
                _Float16 hj = (_Float16)xs[j];
                hi4[j] = hj;
                lo4[j] = (_Float16)(xs[j] - (float)hj);
            }
            _Float16* ed = esl + ej * EST + j4 * 4;
            *(half4*)ed = hi4;          // hi block: halfs [0,16)
            *(half4*)(ed + 16) = lo4;   // lo block: halfs [16,32)
        }

        // ---- 2. issue payload(gs+STEP); 3. issue idx(gs+2*STEP) ----
        if (gs + STEP < eEnd) {
            const _Float16* qs = pq + (size_t)sidN * 128 + 64 + j4 * 16;
            qv0 = *(const half8*)(qs);
            qv1 = *(const half8*)(qs + 8);
            eav = *(const float4*)&ea[(size_t)peN * 16 + j4 * 4];
            if (gs + 2 * STEP < eEnd) {
                int2 ep2 = epair[min(gs + 2 * STEP + ej, emax)];
                sidN = ep2.x;
                peN  = ep2.y;
            }
        }
        __builtin_amdgcn_sched_barrier(0);   // pin load issue before compute

        // ---- 4. lnod: lane computes its local edge's node, then shfl ----
        int Lv = 0;
        {
            int gp = gs + (lane & 15);
            int lo = 0, hi = NPB;
#pragma unroll
            for (int s = 0; s < 4; ++s) {
                int mid = (lo + hi) >> 1;
                bool geq = gp >= endsL[mid];
                lo = geq ? mid : lo;
                hi = geq ? hi : mid;
            }
            Lv = lo;
        }
        const int L0 = __shfl(Lv, quad * 4 + 0, 64);
        const int L1 = __shfl(Lv, quad * 4 + 1, 64);
        const int L2 = __shfl(Lv, quad * 4 + 2, 64);
        const int L3 = __shfl(Lv, quad * 4 + 3, 64);

        // ---- 5. C' : C-in = ps + q, += ea@w1c (MFMA), relu -> t1 ----
        _Float16* qb = tsl + (quad * 4) * TSH + col;
        const float* p0 = &ps[L0 * 68 + col];
        const float* p1 = &ps[L1 * 68 + col];
        const float* p2 = &ps[L2 * 68 + col];
        const float* p3 = &ps[L3 * 68 + col];
        floatx4 acc[4];
#pragma unroll
        for (int nt = 0; nt < 4; ++nt) {
            acc[nt][0] = (float)qb[0 * TSH + nt * 16] + p0[nt * 16];
            acc[nt][1] = (float)qb[1 * TSH + nt * 16] + p1[nt * 16];
            acc[nt][2] = (float)qb[2 * TSH + nt * 16] + p2[nt * 16];
            acc[nt][3] = (float)qb[3 * TSH + nt * 16] + p3[nt * 16];
        }
        half8 af = *(const half8*)&esl[col * EST + quad * 8];
#pragma unroll
        for (int nt = 0; nt < 4; ++nt)
            acc[nt] = __builtin_amdgcn_mfma_f32_16x16x32_f16(
                af, w1cb[nt], acc[nt], 0, 0, 0);
#pragma unroll
        for (int nt = 0; nt < 4; ++nt) {
#pragma unroll
            for (int r = 0; r < 4; ++r)
                qb[r * TSH + nt * 16] = (_Float16)fmaxf(acc[nt][r], 0.f);
        }

        // ---- 6. D : m = t1 @ w2 (MFMA), segmented max into rmu ----
        floatx4 accD[4] = {{0.f,0.f,0.f,0.f},{0.f,0.f,0.f,0.f},
                           {0.f,0.f,0.f,0.f},{0.f,0.f,0.f,0.f}};
#pragma unroll
        for (int kc = 0; kc < 2; ++kc) {
            half8 a = *(const half8*)&tsl[col * TSH + kc * 32 + quad * 8];
#pragma unroll
            for (int nt = 0; nt < 4; ++nt)
                accD[nt] = __builtin_amdgcn_mfma_f32_16x16x32_f16(
                    a, bfrag[nt][kc], accD[nt], 0, 0, 0);
        }
        const int gbase = gs + quad * 4;
#pragma unroll
        for (int nt = 0; nt < 4; ++nt) {
            int curL = -1;
            float best = 0.f;
#pragma unroll
            for (int r = 0; r < 4; ++r) {
                int ge = gbase + r;
                if (ge < eEnd) {
                    int L = (r == 0) ? L0 : (r == 1) ? L1
                          : (r == 2) ? L2 : L3;
                    float v = accD[nt][r];
                    if (L != curL) {
                        if (curL >= 0)
                            atomicMax(&rmu[curL * 68 + nt * 16 + col],
                                      enc(best));
                        curL = L; best = v;
                    } else best = fmaxf(best, v);
                }
            }
            if (curL >= 0)
                atomicMax(&rmu[curL * 68 + nt * 16 + col], enc(best));
        }
    }

    __syncthreads();   // all waves' rmu atomics done

    // ---- final store (+b2, raw agg; BN deferred to consumer) + BN stats ----
    for (int idx = t; idx < NPB * 64; idx += 256) {
        int L = idx >> 6, cc = idx & 63;
        int node = n0 + L;
        float v = 0.f;
        if (node < M) {
            if (endsL[L + 1] > endsL[L]) v = dec(rmu[L * 68 + cc]) + b2[cc];
            hout[(size_t)node * 64 + cc] = v;
        }
        ((float*)rmu)[L * 68 + cc] = v;   // own slot: no race
    }
    __syncthreads();
    if (t < 64) {
        float s = 0.f, s2 = 0.f;
#pragma unroll
        for (int L = 0; L < NPB; ++L) {
            float v = ((float*)rmu)[L * 68 + t];
            s += v;
            s2 = fmaf(v, v, s2);
        }
        atomicAdd(&stats[t], s);
        atomicAdd(&stats[64 + t], s2);
    }
}

// ---------------------------------------------------------------------------
extern "C" void kernel_launch(void* const* d_in, const int* in_sizes, int n_in,
                              void* d_out, int out_size, void* d_ws, size_t ws_size,
                              hipStream_t stream)
{
    const float* x     = (const float*)d_in[0];
    const int*   eidx  = (const int*)  d_in[1];
    const float* ea    = (const float*)d_in[2];
    const float* w_in  = (const float*)d_in[3];
    const float* b_in  = (const float*)d_in[4];
    const float* w1    = (const float*)d_in[5];
    const float* b1    = (const float*)d_in[6];
    const float* w2    = (const float*)d_in[7];
    const float* b2    = (const float*)d_in[8];
    const float* gamma = (const float*)d_in[9];
    const float* beta  = (const float*)d_in[10];
    const float* w_m1  = (const float*)d_in[11];
    const float* b_m1  = (const float*)d_in[12];
    const float* w_m2  = (const float*)d_in[13];
    const float* b_m2  = (const float*)d_in[14];

    const int M = in_sizes[0] / 64;   // n_nodes
    const int E = in_sizes[1] / 2;    // n_edges
    const int* src = eidx;            // edge_index[0]
    const int* tgt = eidx + E;        // edge_index[1] (aggregation target)

    // ws: hagg | pqh | starts | epair | within | part | stats = 35.6 MB
    float* hagg   = (float*)d_ws;
    _Float16* pqh = (_Float16*)(hagg + (size_t)M * 64);
    int* starts   = (int*)(pqh + (size_t)M * 128);
    int2* epair   = (int2*)(starts + M);
    int* within   = (int*)(epair + E);
    const int nb  = (M + 255) / 256;
    int* part     = within + E;
    float* stats  = (float*)(part + nb);
    // d_out scratch: w2h | w1ch — dead before head writes d_out
    _Float16* w2h  = (_Float16*)d_out;
    _Float16* w1ch = (_Float16*)((char*)d_out + 16384);

    dim3 blk(256);
    const int gm64 = (M + 63) / 64;
    const int gE   = (E + 255) / 256;

    // CSR build (atomic-free fill in h0pq_fill) + weight pack (+stats zero)
    (void)hipMemsetAsync(starts, 0, (size_t)M * 4, stream);
    hist_pack<<<gE + 6, blk, 0, stream>>>(tgt, starts, within, E,
                                          w2, w1, w2h, w1ch, stats);
    scan_partial<<<nb, blk, 0, stream>>>(starts, part, M);
    scan_add2<<<nb, blk, 0, stream>>>(starts, part, M, nb);

    // layer 0 p|q GEMM (with in-LDS h0) co-launched with CSR fill
    h0pq_fill<<<gm64 + gE, blk, 0, stream>>>(x, w1, w_in, b_in, pqh, M, gm64,
                                             tgt, src, starts, within, epair, E);
    node_agg<<<(M + NPB - 1) / NPB, blk, 0, stream>>>(pqh, ea,
        starts, epair, w1ch, b1, w2h, b2, hagg, stats, M, E);

    // layer 1
    gemm_pq_bn<<<gm64, blk, 0, stream>>>(hagg, w1 + (size_t)144 * 64, pqh,
                                         stats, gamma, beta, M);
    node_agg<<<(M + NPB - 1) / NPB, blk, 0, stream>>>(pqh, ea,
        starts, epair, w1ch + 2048, b1 + 64, w2h + 4096, b2 + 64,
        hagg, stats + 128, M, E);

    // out = relu(BN1(h) @ w_m1 + b_m1) @ w_m2 + b_m2
    head_fused<<<gm64, blk, 0, stream>>>(hagg, stats + 128, gamma + 64, beta + 64,
        w_m1, b_m1, w_m2, b_m2, (float*)d_out, M);
}

// Round 13
// 399.571 us; speedup vs baseline: 1.3369x; 1.1744x over previous
//
#include <hip/hip_runtime.h>
#include <float.h>

// ---------------------------------------------------------------------------
// MPNN forward.  msg@w1 decomposed: per-node p=h@w1a, q=h@w1b (fused gemm_pq,
// f16 out, BN fused on A-load), per-edge ea@w1c; edge GEMM t1@w2 f16 MFMA.
// R23: node_agg NPB 16->32 (half the blocks -> prologue/epilogue/stats paid
// half as often; ~8 main-loop iters/wave for deeper self-pipelining).  LDS
// 22.6->31.1KB -> 5 blocks/CU.  Binary search 4->5 steps.  All else identical
// to R22.  Pre-commit: if node_agg >= 134us or total >= 469us, revert + call
// roofline (scattered-line wall: 2.4M line-fills/dispatch ~ 1.15 TB/s).
// R22: fill co-launched in h0pq_fill (hidden under GEMM).
// R21: atomic-free CSR fill (within = hist atomicAdd return), int2 epair.
// R19/R20: gemm_h0 fused into h0pq; scan_part2 folded into scan_add2; pack
// fused into hist_pack.
//
// ws: hagg 12.8M | pqh 12.8M | starts 200K | epair 6.4M | within 3.2M |
//   part | stats(256f) = 35.6 MB  (proven bound 38.6 MB).
// d_out scratch: w2h 16K | w1ch 8K (dead before head writes d_out).
// ---------------------------------------------------------------------------

typedef _Float16 half8 __attribute__((ext_vector_type(8)));
typedef _Float16 half4 __attribute__((ext_vector_type(4)));
typedef float floatx4 __attribute__((ext_vector_type(4)));

#define BN_EPS 1e-5f

__device__ __forceinline__ unsigned enc(float f) {
    unsigned u = __float_as_uint(f);
    return (u & 0x80000000u) ? ~u : (u | 0x80000000u);
}
__device__ __forceinline__ float dec(unsigned u) {
    return (u & 0x80000000u) ? __uint_as_float(u & 0x7fffffffu)
                             : __uint_as_float(~u);
}

// ---------------------------------------------------------------------------
// Fused: blocks [0,gm64) = h0+pq GEMM (h=relu(x@w_in+b_in) in-LDS, then
// p|q = h@[w1a|w1b], f16 out); blocks [gm64, gm64+gE) = atomic-free CSR
// fill (pos = starts[tgt]+within, one int2 write).
// ---------------------------------------------------------------------------
__global__ __launch_bounds__(256) void h0pq_fill(
    const float* __restrict__ A, const float* __restrict__ W,
    const float* __restrict__ Wh0, const float* __restrict__ bh0,
    _Float16* __restrict__ PQ, int M, int gm64,
    const int* __restrict__ tgt, const int* __restrict__ src,
    const int* __restrict__ starts, const int* __restrict__ within,
    int2* __restrict__ epair, int E)
{
    __shared__ __align__(16) float Ws[64 * 128];
    __shared__ __align__(16) float As[64 * 68];

    const int t = threadIdx.x;

    if (blockIdx.x >= gm64) {
        // ---- fill role: atomic-free CSR fill, one 8B scattered store ----
        int e = (blockIdx.x - gm64) * 256 + t;
        if (e < E) {
            int pos = starts[tgt[e]] + within[e];
            epair[pos] = make_int2(src[e], e);   // .x = src node, .y = edge
        }
        return;
    }

    const int m0 = blockIdx.x * 64;

    // ---- stage w_in (overlays Ws[0:4096]) + x tile ----
    for (int i = t; i < 64 * 64; i += 256) Ws[i] = Wh0[i];
    for (int rr = 0; rr < 64; rr += 16) {
        int r = rr + (t >> 4);
        int c4 = (t & 15) * 4;
        int row = m0 + r;
        float4 v = make_float4(0.f, 0.f, 0.f, 0.f);
        if (row < M) v = *(const float4*)&A[(size_t)row * 64 + c4];
        *(float4*)&As[r * 68 + c4] = v;
    }
    __syncthreads();

    // ---- h = relu(x @ w_in + b_in), same layout as old gemm_h0 ----
    {
        const int tc = t & 15, tr = t >> 4;
        float4 hacc[4];
        float4 bv = *(const float4*)&bh0[tc * 4];
#pragma unroll
        for (int i = 0; i < 4; ++i) hacc[i] = bv;
#pragma unroll 8
        for (int k = 0; k < 64; ++k) {
            float4 w = *(const float4*)&Ws[k * 64 + tc * 4];
#pragma unroll
            for (int i = 0; i < 4; ++i) {
                float a = As[(tr + i * 16) * 68 + k];
                hacc[i].x = fmaf(a, w.x, hacc[i].x);
                hacc[i].y = fmaf(a, w.y, hacc[i].y);
                hacc[i].z = fmaf(a, w.z, hacc[i].z);
                hacc[i].w = fmaf(a, w.w, hacc[i].w);
            }
        }
        __syncthreads();   // all reads of As/Ws done before overwrite

        // ---- write relu(h) into As; stage W=[w1a|w1b] over Ws ----
#pragma unroll
        for (int i = 0; i < 4; ++i) {
            float4 o = hacc[i];
            o.x = fmaxf(o.x, 0.f); o.y = fmaxf(o.y, 0.f);
            o.z = fmaxf(o.z, 0.f); o.w = fmaxf(o.w, 0.f);
            *(float4*)&As[(tr + i * 16) * 68 + tc * 4] = o;
        }
    }
    for (int i = t; i < 64 * 128; i += 256) {
        int k = i >> 7, n = i & 127;
        Ws[i] = W[(size_t)((n < 64 ? k : 64 + k)) * 64 + (n & 63)];
    }
    __syncthreads();

    const int tc = t & 31, tr = t >> 5;
    float4 acc[8];
#pragma unroll
    for (int i = 0; i < 8; ++i) acc[i] = make_float4(0.f, 0.f, 0.f, 0.f);
#pragma unroll 8
    for (int k = 0; k < 64; ++k) {
        float4 w = *(const float4*)&Ws[k * 128 + tc * 4];
#pragma unroll
        for (int i = 0; i < 8; ++i) {
            float a = As[(tr + i * 8) * 68 + k];
            acc[i].x = fmaf(a, w.x, acc[i].x);
            acc[i].y = fmaf(a, w.y, acc[i].y);
            acc[i].z = fmaf(a, w.z, acc[i].z);
            acc[i].w = fmaf(a, w.w, acc[i].w);
        }
    }
#pragma unroll
    for (int i = 0; i < 8; ++i) {
        int row = m0 + tr + i * 8;
        if (row < M) {
            half4 o = { (_Float16)acc[i].x, (_Float16)acc[i].y,
                        (_Float16)acc[i].z, (_Float16)acc[i].w };
            *(half4*)&PQ[(size_t)row * 128 + tc * 4] = o;
        }
    }
}

// ---------------------------------------------------------------------------
// p|q GEMM with BN+relu fused on A-load (layer 1).
// ---------------------------------------------------------------------------
__global__ __launch_bounds__(256) void gemm_pq_bn(
    const float* __restrict__ A, const float* __restrict__ W,
    _Float16* __restrict__ PQ, const float* __restrict__ stats,
    const float* __restrict__ gamma, const float* __restrict__ beta, int M)
{
    __shared__ __align__(16) float Ws[64 * 128];
    __shared__ __align__(16) float As[64 * 68];

    const int t = threadIdx.x;
    const int m0 = blockIdx.x * 64;

    for (int i = t; i < 64 * 128; i += 256) {
        int k = i >> 7, n = i & 127;
        Ws[i] = W[(size_t)((n < 64 ? k : 64 + k)) * 64 + (n & 63)];
    }
    {
        int c4 = (t & 15) * 4;
        float sc[4], sh[4];
        float invM = 1.f / (float)M;
#pragma unroll
        for (int j = 0; j < 4; ++j) {
            int c = c4 + j;
            float mu = stats[c] * invM;
            float var = fmaxf(stats[64 + c] * invM - mu * mu, 0.f);
            float s = gamma[c] * rsqrtf(var + BN_EPS);
            sc[j] = s; sh[j] = beta[c] - mu * s;
        }
        for (int rr = 0; rr < 64; rr += 16) {
            int r = rr + (t >> 4);
            int row = m0 + r;
            float4 v = make_float4(0.f, 0.f, 0.f, 0.f);
            if (row < M) v = *(const float4*)&A[(size_t)row * 64 + c4];
            v.x = fmaxf(fmaf(v.x, sc[0], sh[0]), 0.f);
            v.y = fmaxf(fmaf(v.y, sc[1], sh[1]), 0.f);
            v.z = fmaxf(fmaf(v.z, sc[2], sh[2]), 0.f);
            v.w = fmaxf(fmaf(v.w, sc[3], sh[3]), 0.f);
            *(float4*)&As[r * 68 + c4] = v;
        }
    }
    __syncthreads();

    const int tc = t & 31, tr = t >> 5;
    float4 acc[8];
#pragma unroll
    for (int i = 0; i < 8; ++i) acc[i] = make_float4(0.f, 0.f, 0.f, 0.f);
#pragma unroll 8
    for (int k = 0; k < 64; ++k) {
        float4 w = *(const float4*)&Ws[k * 128 + tc * 4];
#pragma unroll
        for (int i = 0; i < 8; ++i) {
            float a = As[(tr + i * 8) * 68 + k];
            acc[i].x = fmaf(a, w.x, acc[i].x);
            acc[i].y = fmaf(a, w.y, acc[i].y);
            acc[i].z = fmaf(a, w.z, acc[i].z);
            acc[i].w = fmaf(a, w.w, acc[i].w);
        }
    }
#pragma unroll
    for (int i = 0; i < 8; ++i) {
        int row = m0 + tr + i * 8;
        if (row < M) {
            half4 o = { (_Float16)acc[i].x, (_Float16)acc[i].y,
                        (_Float16)acc[i].z, (_Float16)acc[i].w };
            *(half4*)&PQ[(size_t)row * 128 + tc * 4] = o;
        }
    }
}

// ---------------------------------------------------------------------------
// Fused head: out = relu(BN(h) @ w_m1 + b_m1) @ w_m2 + b_m2
// ---------------------------------------------------------------------------
__global__ __launch_bounds__(256) void head_fused(
    const float* __restrict__ hagg, const float* __restrict__ stats,
    const float* __restrict__ gamma, const float* __restrict__ beta,
    const float* __restrict__ w_m1, const float* __restrict__ b_m1,
    const float* __restrict__ w_m2, const float* __restrict__ b_m2,
    float* __restrict__ out, int M)
{
    __shared__ __align__(16) float Ws1[64 * 64];
    __shared__ __align__(16) float Ws2[64 * 32];
    __shared__ __align__(16) float As[64 * 68];
    __shared__ __align__(16) float Ts[64 * 68];

    const int t = threadIdx.x;
    const int m0 = blockIdx.x * 64;

    for (int i = t; i < 64 * 64; i += 256) Ws1[i] = w_m1[i];
    for (int i = t; i < 64 * 32; i += 256) Ws2[i] = w_m2[i];
    {
        int c4 = (t & 15) * 4;
        float sc[4], sh[4];
        float invM = 1.f / (float)M;
#pragma unroll
        for (int j = 0; j < 4; ++j) {
            int c = c4 + j;
            float mu = stats[c] * invM;
            float var = fmaxf(stats[64 + c] * invM - mu * mu, 0.f);
            float s = gamma[c] * rsqrtf(var + BN_EPS);
            sc[j] = s; sh[j] = beta[c] - mu * s;
        }
        for (int rr = 0; rr < 64; rr += 16) {
            int r = rr + (t >> 4);
            int row = m0 + r;
            float4 v = make_float4(0.f, 0.f, 0.f, 0.f);
            if (row < M) v = *(const float4*)&hagg[(size_t)row * 64 + c4];
            v.x = fmaxf(fmaf(v.x, sc[0], sh[0]), 0.f);
            v.y = fmaxf(fmaf(v.y, sc[1], sh[1]), 0.f);
            v.z = fmaxf(fmaf(v.z, sc[2], sh[2]), 0.f);
            v.w = fmaxf(fmaf(v.w, sc[3], sh[3]), 0.f);
            *(float4*)&As[r * 68 + c4] = v;
        }
    }
    __syncthreads();

    {
        const int tc = t & 15, tr = t >> 4;
        float4 acc[4];
        float4 bv = *(const float4*)&b_m1[tc * 4];
#pragma unroll
        for (int i = 0; i < 4; ++i) acc[i] = bv;
#pragma unroll 8
        for (int k = 0; k < 64; ++k) {
            float4 w = *(const float4*)&Ws1[k * 64 + tc * 4];
#pragma unroll
            for (int i = 0; i < 4; ++i) {
                float a = As[(tr + i * 16) * 68 + k];
                acc[i].x = fmaf(a, w.x, acc[i].x);
                acc[i].y = fmaf(a, w.y, acc[i].y);
                acc[i].z = fmaf(a, w.z, acc[i].z);
                acc[i].w = fmaf(a, w.w, acc[i].w);
            }
        }
#pragma unroll
        for (int i = 0; i < 4; ++i) {
            float4 o = acc[i];
            o.x = fmaxf(o.x, 0.f); o.y = fmaxf(o.y, 0.f);
            o.z = fmaxf(o.z, 0.f); o.w = fmaxf(o.w, 0.f);
            *(float4*)&Ts[(tr + i * 16) * 68 + tc * 4] = o;
        }
    }
    __syncthreads();

    {
        const int tc = t & 7, tr = t >> 3;
        float4 acc[2];
        float4 bv = *(const float4*)&b_m2[tc * 4];
        acc[0] = bv; acc[1] = bv;
#pragma unroll 8
        for (int k = 0; k < 64; ++k) {
            float4 w = *(const float4*)&Ws2[k * 32 + tc * 4];
#pragma unroll
            for (int i = 0; i < 2; ++i) {
                float a = Ts[(tr + i * 32) * 68 + k];
                acc[i].x = fmaf(a, w.x, acc[i].x);
                acc[i].y = fmaf(a, w.y, acc[i].y);
                acc[i].z = fmaf(a, w.z, acc[i].z);
                acc[i].w = fmaf(a, w.w, acc[i].w);
            }
        }
#pragma unroll
        for (int i = 0; i < 2; ++i) {
            int row = m0 + tr + i * 32;
            if (row < M) *(float4*)&out[(size_t)row * 32 + tc * 4] = acc[i];
        }
    }
}

// ---------------------------------------------------------------------------
// CSR build: hist(+within +pack fused) -> scan_partial -> scan_add2
// (fill lives in h0pq_fill)
// ---------------------------------------------------------------------------
__global__ __launch_bounds__(256) void hist_pack(const int* __restrict__ tgt,
    int* __restrict__ cnt, int* __restrict__ within, int E,
    const float* __restrict__ w2, const float* __restrict__ w1,
    _Float16* __restrict__ w2h, _Float16* __restrict__ w1ch,
    float* __restrict__ stats)
{
    const int gE = (E + 255) >> 8;
    const int b = blockIdx.x;
    if (b < gE) {
        int e = b * 256 + threadIdx.x;
        if (e < E) within[e] = atomicAdd(&cnt[tgt[e]], 1);
        return;
    }
    int id = (b - gE) * 256 + threadIdx.x;
    if (id < 256) stats[id] = 0.f;
    if (id < 1024) {
        int l = id >> 9, rem = id & 511;
        int frag = rem >> 6, lane = rem & 63;
        int nt = frag >> 1, kc = frag & 1;
        const float* W = w2 + (size_t)l * 4096;
        _Float16* O = w2h + (size_t)l * 4096 + (frag * 64 + lane) * 8;
        int n = nt * 16 + (lane & 15);
        int k0 = kc * 32 + (lane >> 4) * 8;
#pragma unroll
        for (int j = 0; j < 8; ++j) O[j] = (_Float16)W[(k0 + j) * 64 + n];
    } else if (id < 1536) {
        // w1ch: B[k][n] = w1c[k & 15][n], K=32 (duplicated halves), 4 nt tiles
        int rem2 = id - 1024;
        int l = rem2 >> 8, rem = rem2 & 255;
        int nt = rem >> 6, lane = rem & 63;
        const float* W1C = w1 + (size_t)l * 144 * 64 + 128 * 64;
        _Float16* O = w1ch + (size_t)l * 2048 + (nt * 64 + lane) * 8;
        int n = nt * 16 + (lane & 15);
        int k0 = (lane >> 4) * 8;
#pragma unroll
        for (int j = 0; j < 8; ++j)
            O[j] = (_Float16)W1C[((k0 + j) & 15) * 64 + n];
    }
}

__global__ __launch_bounds__(256) void scan_partial(const int* __restrict__ cnt,
                                                    int* __restrict__ part, int M)
{
    __shared__ int s[256];
    int i = blockIdx.x * 256 + threadIdx.x;
    s[threadIdx.x] = (i < M) ? cnt[i] : 0;
    __syncthreads();
    for (int off = 128; off > 0; off >>= 1) {
        if (threadIdx.x < off) s[threadIdx.x] += s[threadIdx.x + off];
        __syncthreads();
    }
    if (threadIdx.x == 0) part[blockIdx.x] = s[0];
}

// scan_add2: block computes its own prefix offset (sum part[0..bid)), then
// in-block exclusive scan of cnt.  Output = exclusive starts (unmutated).
__global__ __launch_bounds__(256) void scan_add2(int* __restrict__ cnt,
    const int* __restrict__ part, int M, int nb)
{
    __shared__ int s[256];
    const int t = threadIdx.x;
    const int bid = blockIdx.x;

    int v0 = (t < bid && t < nb) ? part[t] : 0;
    s[t] = v0;
    __syncthreads();
    for (int off = 128; off > 0; off >>= 1) {
        if (t < off) s[t] += s[t + off];
        __syncthreads();
    }
    const int base = s[0];
    __syncthreads();

    int i = bid * 256 + t;
    int v = (i < M) ? cnt[i] : 0;
    s[t] = v;
    __syncthreads();
    for (int off = 1; off < 256; off <<= 1) {
        int a = (t >= off) ? s[t - off] : 0;
        __syncthreads();
        s[t] += a;
        __syncthreads();
    }
    if (i < M) cnt[i] = base + s[t] - v;   // exclusive
}

// ---------------------------------------------------------------------------
// Fused per-node edge-MLP + segmented max + BN stats.
//   R18 structure: barrier-free per-wave micro-tile pipeline (16 edges/group,
//   private LDS slice per wave, no __syncthreads in main loop).  ea@w1c via
//   MFMA (exact hi/lo split), C'+D fused, lnod via binary search + shfl.
//   R23: NPB=32 (amortize prologue/epilogue; 5-step binary search).
// ---------------------------------------------------------------------------
#define NPB 32
#define WED 16     // edges per wave micro-tile
#define TSH 72     // t1/q stride in halfs (144 B -> 2-way b128, free)
#define EST 40     // eash stride in halfs (80 B, 16B-aligned rows, 2-way)
#define QSL (WED * TSH)   // 1152 halfs per wave slice
#define ESL (WED * EST)   //  640 halfs per wave slice

__global__ __launch_bounds__(256, 4) void node_agg(
    const _Float16* __restrict__ pq, const float* __restrict__ ea,
    const int* __restrict__ starts, const int2* __restrict__ epair,
    const _Float16* __restrict__ w1cbG, const float* __restrict__ b1,
    const _Float16* __restrict__ w2h, const float* __restrict__ b2,
    float* __restrict__ hout, float* __restrict__ stats, int M, int E)
{
    __shared__ __align__(16) _Float16 t1h[4 * QSL];    // 9.0 KB
    __shared__ __align__(16) _Float16 eash[4 * ESL];   // 5.0 KB
    __shared__ __align__(16) float ps[NPB * 68];       // 8.5 KB
    __shared__ __align__(16) unsigned rmu[NPB * 68];   // 8.5 KB
    __shared__ int endsL[NPB + 1];
    // total ~31.1 KB -> 5 blocks/CU (LDS-limited)

    const int t = threadIdx.x;
    const int lane = t & 63;
    const int wid = t >> 6;
    const int n0 = blockIdx.x * NPB;
    const int c = lane;
    const int quad = lane >> 4;
    const int col = lane & 15;
    const int ej = lane >> 2;    // local edge 0..15 (4 lanes per edge)
    const int j4 = lane & 3;

    if (t <= NPB) {
        int n = n0 + t;
        endsL[t] = (n < M) ? starts[n] : E;   // start of node n (E sentinel)
    }
    for (int nn = wid; nn < NPB; nn += 4) {
        int node = n0 + nn;
        ps[nn * 68 + c] =
            ((node < M) ? (float)pq[(size_t)node * 128 + c] : 0.f) + b1[c];
    }
    for (int i = t; i < NPB * 68; i += 256) rmu[i] = 0u;   // 0 < enc(anything)

    half8 bfrag[4][2];
#pragma unroll
    for (int nt = 0; nt < 4; ++nt)
#pragma unroll
        for (int kc = 0; kc < 2; ++kc)
            bfrag[nt][kc] = *(const half8*)(w2h + ((nt * 2 + kc) * 64 + lane) * 8);
    half8 w1cb[4];
#pragma unroll
    for (int nt = 0; nt < 4; ++nt)
        w1cb[nt] = *(const half8*)(w1cbG + (nt * 64 + lane) * 8);

    __syncthreads();

    const int eBeg = endsL[0], eEnd = endsL[NPB];
    const int emax = (eEnd > 0) ? eEnd - 1 : 0;
    const int STEP = 4 * WED;                 // 64
    const int g0 = eBeg + wid * WED;          // this wave's first group

    _Float16* tsl = t1h + wid * QSL;          // private slices
    _Float16* esl = eash + wid * ESL;

    // per-wave prefetch state (16 VGPR): payload(g), indices(g+1)
    half8  qv0 = {}, qv1 = {};
    float4 eav = make_float4(0.f, 0.f, 0.f, 0.f);
    int sidN = 0, peN = 0;

    if (g0 < eEnd) {
        int2 ep0 = epair[min(g0 + ej, emax)];
        const _Float16* qs = pq + (size_t)ep0.x * 128 + 64 + j4 * 16;
        qv0 = *(const half8*)(qs);
        qv1 = *(const half8*)(qs + 8);
        eav = *(const float4*)&ea[(size_t)ep0.y * 16 + j4 * 4];
        int2 ep1 = epair[min(g0 + STEP + ej, emax)];
        sidN = ep1.x;
        peN  = ep1.y;
    }

    for (int gs = g0; gs < eEnd; gs += STEP) {
        // ---- 1. write payload(gs) into own slice (same-wave DS order) ----
        {
            _Float16* qd = tsl + ej * TSH + j4 * 16;
            *(half8*)qd = qv0;
            *(half8*)(qd + 8) = qv1;

            float xs[4] = { eav.x, eav.y, eav.z, eav.w };
            half4 hi4, lo4;
#pragma unroll
            for (int j = 0; j < 4; ++j) {
                _Float16 hj = (_Float16)xs[j];
                hi4[j] = hj;
                lo4[j] = (_Float16)(xs[j] - (float)hj);
            }
            _Float16* ed = esl + ej * EST + j4 * 4;
            *(half4*)ed = hi4;          // hi block: halfs [0,16)
            *(half4*)(ed + 16) = lo4;   // lo block: halfs [16,32)
        }

        // ---- 2. issue payload(gs+STEP); 3. issue idx(gs+2*STEP) ----
        if (gs + STEP < eEnd) {
            const _Float16* qs = pq + (size_t)sidN * 128 + 64 + j4 * 16;
            qv0 = *(const half8*)(qs);
            qv1 = *(const half8*)(qs + 8);
            eav = *(const float4*)&ea[(size_t)peN * 16 + j4 * 4];
            if (gs + 2 * STEP < eEnd) {
                int2 ep2 = epair[min(gs + 2 * STEP + ej, emax)];
                sidN = ep2.x;
                peN  = ep2.y;
            }
        }
        __builtin_amdgcn_sched_barrier(0);   // pin load issue before compute

        // ---- 4. lnod: lane computes its local edge's node, then shfl ----
        int Lv = 0;
        {
            int gp = gs + (lane & 15);
            int lo = 0, hi = NPB;
#pragma unroll
            for (int s = 0; s < 5; ++s) {
                int mid = (lo + hi) >> 1;
                bool geq = gp >= endsL[mid];
                lo = geq ? mid : lo;
                hi = geq ? hi : mid;
            }
            Lv = lo;
        }
        const int L0 = __shfl(Lv, quad * 4 + 0, 64);
        const int L1 = __shfl(Lv, quad * 4 + 1, 64);
        const int L2 = __shfl(Lv, quad * 4 + 2, 64);
        const int L3 = __shfl(Lv, quad * 4 + 3, 64);

        // ---- 5. C' : C-in = ps + q, += ea@w1c (MFMA), relu -> t1 ----
        _Float16* qb = tsl + (quad * 4) * TSH + col;
        const float* p0 = &ps[L0 * 68 + col];
        const float* p1 = &ps[L1 * 68 + col];
        const float* p2 = &ps[L2 * 68 + col];
        const float* p3 = &ps[L3 * 68 + col];
        floatx4 acc[4];
#pragma unroll
        for (int nt = 0; nt < 4; ++nt) {
            acc[nt][0] = (float)qb[0 * TSH + nt * 16] + p0[nt * 16];
            acc[nt][1] = (float)qb[1 * TSH + nt * 16] + p1[nt * 16];
            acc[nt][2] = (float)qb[2 * TSH + nt * 16] + p2[nt * 16];
            acc[nt][3] = (float)qb[3 * TSH + nt * 16] + p3[nt * 16];
        }
        half8 af = *(const half8*)&esl[col * EST + quad * 8];
#pragma unroll
        for (int nt = 0; nt < 4; ++nt)
            acc[nt] = __builtin_amdgcn_mfma_f32_16x16x32_f16(
                af, w1cb[nt], acc[nt], 0, 0, 0);
#pragma unroll
        for (int nt = 0; nt < 4; ++nt) {
#pragma unroll
            for (int r = 0; r < 4; ++r)
                qb[r * TSH + nt * 16] = (_Float16)fmaxf(acc[nt][r], 0.f);
        }

        // ---- 6. D : m = t1 @ w2 (MFMA), segmented max into rmu ----
        floatx4 accD[4] = {{0.f,0.f,0.f,0.f},{0.f,0.f,0.f,0.f},
                           {0.f,0.f,0.f,0.f},{0.f,0.f,0.f,0.f}};
#pragma unroll
        for (int kc = 0; kc < 2; ++kc) {
            half8 a = *(const half8*)&tsl[col * TSH + kc * 32 + quad * 8];
#pragma unroll
            for (int nt = 0; nt < 4; ++nt)
                accD[nt] = __builtin_amdgcn_mfma_f32_16x16x32_f16(
                    a, bfrag[nt][kc], accD[nt], 0, 0, 0);
        }
        const int gbase = gs + quad * 4;
#pragma unroll
        for (int nt = 0; nt < 4; ++nt) {
            int curL = -1;
            float best = 0.f;
#pragma unroll
            for (int r = 0; r < 4; ++r) {
                int ge = gbase + r;
                if (ge < eEnd) {
                    int L = (r == 0) ? L0 : (r == 1) ? L1
                          : (r == 2) ? L2 : L3;
                    float v = accD[nt][r];
                    if (L != curL) {
                        if (curL >= 0)
                            atomicMax(&rmu[curL * 68 + nt * 16 + col],
                                      enc(best));
                        curL = L; best = v;
                    } else best = fmaxf(best, v);
                }
            }
            if (curL >= 0)
                atomicMax(&rmu[curL * 68 + nt * 16 + col], enc(best));
        }
    }

    __syncthreads();   // all waves' rmu atomics done

    // ---- final store (+b2, raw agg; BN deferred to consumer) + BN stats ----
    for (int idx = t; idx < NPB * 64; idx += 256) {
        int L = idx >> 6, cc = idx & 63;
        int node = n0 + L;
        float v = 0.f;
        if (node < M) {
            if (endsL[L + 1] > endsL[L]) v = dec(rmu[L * 68 + cc]) + b2[cc];
            hout[(size_t)node * 64 + cc] = v;
        }
        ((float*)rmu)[L * 68 + cc] = v;   // own slot: no race
    }
    __syncthreads();
    if (t < 64) {
        float s = 0.f, s2 = 0.f;
#pragma unroll
        for (int L = 0; L < NPB; ++L) {
            float v = ((float*)rmu)[L * 68 + t];
            s += v;
            s2 = fmaf(v, v, s2);
        }
        atomicAdd(&stats[t], s);
        atomicAdd(&stats[64 + t], s2);
    }
}

// ---------------------------------------------------------------------------
extern "C" void kernel_launch(void* const* d_in, const int* in_sizes, int n_in,
                              void* d_out, int out_size, void* d_ws, size_t ws_size,
                              hipStream_t stream)
{
    const float* x     = (const float*)d_in[0];
    const int*   eidx  = (const int*)  d_in[1];
    const float* ea    = (const float*)d_in[2];
    const float* w_in  = (const float*)d_in[3];
    const float* b_in  = (const float*)d_in[4];
    const float* w1    = (const float*)d_in[5];
    const float* b1    = (const float*)d_in[6];
    const float* w2    = (const float*)d_in[7];
    const float* b2    = (const float*)d_in[8];
    const float* gamma = (const float*)d_in[9];
    const float* beta  = (const float*)d_in[10];
    const float* w_m1  = (const float*)d_in[11];
    const float* b_m1  = (const float*)d_in[12];
    const float* w_m2  = (const float*)d_in[13];
    const float* b_m2  = (const float*)d_in[14];

    const int M = in_sizes[0] / 64;   // n_nodes
    const int E = in_sizes[1] / 2;    // n_edges
    const int* src = eidx;            // edge_index[0]
    const int* tgt = eidx + E;        // edge_index[1] (aggregation target)

    // ws: hagg | pqh | starts | epair | within | part | stats = 35.6 MB
    float* hagg   = (float*)d_ws;
    _Float16* pqh = (_Float16*)(hagg + (size_t)M * 64);
    int* starts   = (int*)(pqh + (size_t)M * 128);
    int2* epair   = (int2*)(starts + M);
    int* within   = (int*)(epair + E);
    const int nb  = (M + 255) / 256;
    int* part     = within + E;
    float* stats  = (float*)(part + nb);
    // d_out scratch: w2h | w1ch — dead before head writes d_out
    _Float16* w2h  = (_Float16*)d_out;
    _Float16* w1ch = (_Float16*)((char*)d_out + 16384);

    dim3 blk(256);
    const int gm64 = (M + 63) / 64;
    const int gE   = (E + 255) / 256;

    // CSR build (atomic-free fill in h0pq_fill) + weight pack (+stats zero)
    (void)hipMemsetAsync(starts, 0, (size_t)M * 4, stream);
    hist_pack<<<gE + 6, blk, 0, stream>>>(tgt, starts, within, E,
                                          w2, w1, w2h, w1ch, stats);
    scan_partial<<<nb, blk, 0, stream>>>(starts, part, M);
    scan_add2<<<nb, blk, 0, stream>>>(starts, part, M, nb);

    // layer 0 p|q GEMM (with in-LDS h0) co-launched with CSR fill
    h0pq_fill<<<gm64 + gE, blk, 0, stream>>>(x, w1, w_in, b_in, pqh, M, gm64,
                                             tgt, src, starts, within, epair, E);
    node_agg<<<(M + NPB - 1) / NPB, blk, 0, stream>>>(pqh, ea,
        starts, epair, w1ch, b1, w2h, b2, hagg, stats, M, E);

    // layer 1
    gemm_pq_bn<<<gm64, blk, 0, stream>>>(hagg, w1 + (size_t)144 * 64, pqh,
                                         stats, gamma, beta, M);
    node_agg<<<(M + NPB - 1) / NPB, blk, 0, stream>>>(pqh, ea,
        starts, epair, w1ch + 2048, b1 + 64, w2h + 4096, b2 + 64,
        hagg, stats + 128, M, E);

    // out = relu(BN1(h) @ w_m1 + b_m1) @ w_m2 + b_m2
    head_fused<<<gm64, blk, 0, stream>>>(hagg, stats + 128, gamma + 64, beta + 64,
        w_m1, b_m1, w_m2, b_m2, (float*)d_out, M);
}